// Round 2
// baseline (483.915 us; speedup 1.0000x reference)
//
#include <hip/hip_runtime.h>

#define DEV __device__ __forceinline__

typedef __attribute__((ext_vector_type(4))) float f32x4;
typedef __attribute__((ext_vector_type(4))) unsigned short u16x4;
typedef __attribute__((ext_vector_type(8))) __bf16 bf16x8;

constexpr int NB = 16, SL = 2048, EM = 1024, DKD = 128;

DEV unsigned short f2bf(float f) {           // fp32 -> bf16 RNE
  unsigned int u = __float_as_uint(f);
  u += 0x7FFFu + ((u >> 16) & 1u);
  return (unsigned short)(u >> 16);
}

DEV f32x4 mfma16(bf16x8 a, bf16x8 b, f32x4 c) {
  return __builtin_amdgcn_mfma_f32_16x16x32_bf16(a, b, c, 0, 0, 0);
}

// async global->LDS DMA, 16B per lane; lds dst = wave-uniform base + lane*16
DEV void dma16(const void* g, void* l) {
  __builtin_amdgcn_global_load_lds(
      (const __attribute__((address_space(1))) unsigned int*)g,
      (__attribute__((address_space(3))) unsigned int*)l, 16, 0, 0);
}

DEV bf16x8 cvt8(f32x4 a, f32x4 b) {
  bf16x8 r;
  r[0] = (__bf16)a[0]; r[1] = (__bf16)a[1]; r[2] = (__bf16)a[2]; r[3] = (__bf16)a[3];
  r[4] = (__bf16)b[0]; r[5] = (__bf16)b[1]; r[6] = (__bf16)b[2]; r[7] = (__bf16)b[3];
  return r;
}

#define SBAR() __builtin_amdgcn_sched_barrier(0)

// ---------------------------------------------------------------------------
// prep_w: Wq/Wk/Wv fp32 [1024][128] -> bf16, tiled+swizzled, DMA-ready.
// Chunk t = ((m*16 + kc)*128 + n)*8 + p holds W_m[k = kc*64 + (p^(n&7))*8 + e][n].
// LDS-staged: coalesced reads + coalesced writes.
// ---------------------------------------------------------------------------
__global__ __launch_bounds__(256) void prep_w(
    const float* __restrict__ Wq, const float* __restrict__ Wk,
    const float* __restrict__ Wv, unsigned short* __restrict__ Wt)
{
  __shared__ unsigned short T[64 * 128];     // [kk][n] bf16
  const int tid = threadIdx.x;
  const int m = blockIdx.x >> 4, kc = blockIdx.x & 15;   // 48 blocks
  const float* W = (m == 0) ? Wq : ((m == 1) ? Wk : Wv);
  #pragma unroll
  for (int it = 0; it < 8; ++it) {
    int idx = it * 256 + tid;                // 2048 f32x4 chunks
    int kk = idx >> 5, n4 = (idx & 31) * 4;
    f32x4 w4 = *(const f32x4*)(W + (size_t)(kc * 64 + kk) * DKD + n4);
    *(u16x4*)&T[kk * 128 + n4] =
        u16x4{ f2bf(w4[0]), f2bf(w4[1]), f2bf(w4[2]), f2bf(w4[3]) };
  }
  __syncthreads();
  #pragma unroll
  for (int it = 0; it < 4; ++it) {
    int idx = it * 256 + tid;                // 1024 out chunks, p fastest
    int p = idx & 7, n = idx >> 3;
    int c = p ^ (n & 7);
    unsigned short v[8];
    #pragma unroll
    for (int e = 0; e < 8; ++e) v[e] = T[(c * 8 + e) * 128 + n];
    size_t t = ((size_t)(m * 16 + kc) * 128 + n) * 8 + p;
    *(u16x4*)(Wt + t * 8)     = u16x4{v[0], v[1], v[2], v[3]};
    *(u16x4*)(Wt + t * 8 + 4) = u16x4{v[4], v[5], v[6], v[7]};
  }
}

// ---------------------------------------------------------------------------
// proj_qk: Q,K = ctx @ {Wq,Wk}. M-tile 64 (grid 512), N = 256 (Q|K).
// T3/T4 schedule: raw s_barrier + counted vmcnt(16) so the A-prefetch
// (issued one iteration ahead, double-buffered af) and the weight DMA
// (issued post-barrier into the opposite buffer) ride across barriers.
// Nothing is ever drained to vmcnt(0) in the main loop.
//
// Per-step issue order (pinned by sched_barrier(0)):
//   r1: cvt af_next <- An(kc+1)     [compiler waits An(kc+1) only]
//   r2: issue An(kc+2) glb loads    [16 ops/wave, stay in flight]
//   r3: s_waitcnt vmcnt(16)         [drains DMA(kc) exactly] ; s_barrier
//   r4: issue DMA(kc+1)->Ws[other]  [8 ops/wave] ; MFMA(kc)
// Tail: prefetch indices CLAMPED (not skipped) so vmcnt counts stay uniform.
// ---------------------------------------------------------------------------
#define QK_STEP(KC, AFC, AFN, RBUF, WBUF)                                     \
  {                                                                           \
    _Pragma("unroll")                                                         \
    for (int rt = 0; rt < 4; ++rt)                                            \
      _Pragma("unroll")                                                       \
      for (int ks = 0; ks < 2; ++ks)                                          \
        AFN[rt][ks] = cvt8(An[rt][ks][0], An[rt][ks][1]);                     \
    SBAR();                                                                   \
    { const int kp = ((KC) + 2 < 16) ? ((KC) + 2) : 15;                       \
      _Pragma("unroll")                                                       \
      for (int rt = 0; rt < 4; ++rt)                                          \
        _Pragma("unroll")                                                     \
        for (int ks = 0; ks < 2; ++ks) {                                      \
          An[rt][ks][0] = *(const f32x4*)(ab[rt] + kp * 64 + ks * 32);        \
          An[rt][ks][1] = *(const f32x4*)(ab[rt] + kp * 64 + ks * 32 + 4);    \
        } }                                                                   \
    SBAR();                                                                   \
    __asm__ volatile("s_waitcnt vmcnt(16)" ::: "memory");                     \
    __builtin_amdgcn_s_barrier();                                             \
    SBAR();                                                                   \
    { const int kn = ((KC) + 1 < 16) ? ((KC) + 1) : 15;                       \
      _Pragma("unroll")                                                       \
      for (int it = 0; it < 8; ++it) {                                        \
        int s = it * 256 + tid;                                               \
        int mtx = s >> 10, sl = s & 1023;                                     \
        dma16(Wt + ((size_t)mtx * 16384 + (size_t)kn * 1024 + sl) * 8,        \
              (char*)Ws[WBUF] + (it * 256 + wave * 64) * 16);                 \
      } }                                                                     \
    { const unsigned short* wb = Ws[RBUF];                                    \
      _Pragma("unroll")                                                       \
      for (int lo = 0; lo < 4; ++lo) {                                        \
        const int nrow = (wave * 4 + lo) * 16 + mm;                           \
        _Pragma("unroll")                                                     \
        for (int ks = 0; ks < 2; ++ks) {                                      \
          const int pp = (ks * 4 + quad) ^ (mm & 7);                          \
          bf16x8 bf = *(const bf16x8*)(wb + nrow * 64 + pp * 8);              \
          _Pragma("unroll")                                                   \
          for (int rt = 0; rt < 4; ++rt)                                      \
            acc[rt][lo] = mfma16(AFC[rt][ks], bf, acc[rt][lo]);               \
        }                                                                     \
      } }                                                                     \
    SBAR();                                                                   \
  }

__global__ __launch_bounds__(256, 2) void proj_qk(
    const float* __restrict__ ctx, const unsigned short* __restrict__ Wt,
    const int* __restrict__ lens, unsigned short* __restrict__ Qo,
    unsigned short* __restrict__ Kz)
{
  __shared__ unsigned short Ws[2][256 * 64];
  const int tid = threadIdx.x;
  const int wave = tid >> 6, lane = tid & 63;
  const int quad = lane >> 4, mm = lane & 15;
  const int rb = blockIdx.x * 64;

  f32x4 acc[4][4];
  #pragma unroll
  for (int i = 0; i < 4; ++i)
    #pragma unroll
    for (int j = 0; j < 4; ++j) acc[i][j] = f32x4{0.f, 0.f, 0.f, 0.f};

  const float* ab[4];
  #pragma unroll
  for (int rt = 0; rt < 4; ++rt)
    ab[rt] = ctx + (size_t)(rb + rt * 16 + mm) * EM + quad * 8;

  f32x4 An[4][2][2];
  bf16x8 afA[4][2], afB[4][2];

  // ---- prologue: An(0)->cvt afA; issue An(1); issue DMA(0)->Ws[0] ----
  #pragma unroll
  for (int rt = 0; rt < 4; ++rt)
    #pragma unroll
    for (int ks = 0; ks < 2; ++ks) {
      An[rt][ks][0] = *(const f32x4*)(ab[rt] + ks * 32);
      An[rt][ks][1] = *(const f32x4*)(ab[rt] + ks * 32 + 4);
    }
  #pragma unroll
  for (int rt = 0; rt < 4; ++rt)
    #pragma unroll
    for (int ks = 0; ks < 2; ++ks) afA[rt][ks] = cvt8(An[rt][ks][0], An[rt][ks][1]);
  SBAR();
  #pragma unroll
  for (int rt = 0; rt < 4; ++rt)
    #pragma unroll
    for (int ks = 0; ks < 2; ++ks) {
      An[rt][ks][0] = *(const f32x4*)(ab[rt] + 64 + ks * 32);
      An[rt][ks][1] = *(const f32x4*)(ab[rt] + 64 + ks * 32 + 4);
    }
  SBAR();
  #pragma unroll
  for (int it = 0; it < 8; ++it) {
    int s = it * 256 + tid;
    int mtx = s >> 10, sl = s & 1023;
    dma16(Wt + ((size_t)mtx * 16384 + sl) * 8,
          (char*)Ws[0] + (it * 256 + wave * 64) * 16);
  }
  SBAR();

  #pragma unroll 1
  for (int t = 0; t < 8; ++t) {
    const int kc = t * 2;
    QK_STEP(kc,     afA, afB, 0, 1)
    QK_STEP(kc + 1, afB, afA, 1, 0)
  }

  const int len = lens[blockIdx.x >> 5];
  const float SCALE = 1.4426950408889634f * 0.08838834764831845f; // log2e/sqrt(128)
  #pragma unroll
  for (int rt = 0; rt < 4; ++rt)
    #pragma unroll
    for (int lo = 0; lo < 4; ++lo) {
      const int ctg = wave * 4 + lo;
      #pragma unroll
      for (int reg = 0; reg < 4; ++reg) {
        const int row = rb + rt * 16 + quad * 4 + reg;
        const int j = row & (SL - 1);
        const float val = acc[rt][lo][reg];
        if (ctg < 8) {
          const int d = ctg * 16 + mm;
          Qo[(size_t)row * DKD + d] = f2bf(val * ((j < len) ? SCALE : 0.f));
        } else {
          const int d = (ctg - 8) * 16 + mm;
          Kz[(size_t)row * DKD + (((d >> 3) ^ (j & 15)) * 8) + (d & 7)] = f2bf(val);
        }
      }
    }
}

// ---------------------------------------------------------------------------
// proj_v: V = x @ Wv, same T3/T4 counted-vmcnt schedule as proj_qk.
// Output transposed+window-swizzled Vz[b][d][j-windows].
// ---------------------------------------------------------------------------
#define V_STEP(KC, AFC, AFN, RBUF, WBUF)                                      \
  {                                                                           \
    _Pragma("unroll")                                                         \
    for (int rt = 0; rt < 4; ++rt)                                            \
      _Pragma("unroll")                                                       \
      for (int ks = 0; ks < 2; ++ks)                                          \
        AFN[rt][ks] = cvt8(An[rt][ks][0], An[rt][ks][1]);                     \
    SBAR();                                                                   \
    { const int kp = ((KC) + 2 < 16) ? ((KC) + 2) : 15;                       \
      _Pragma("unroll")                                                       \
      for (int rt = 0; rt < 4; ++rt)                                          \
        _Pragma("unroll")                                                     \
        for (int ks = 0; ks < 2; ++ks) {                                      \
          An[rt][ks][0] = *(const f32x4*)(ab[rt] + kp * 64 + ks * 32);        \
          An[rt][ks][1] = *(const f32x4*)(ab[rt] + kp * 64 + ks * 32 + 4);    \
        } }                                                                   \
    SBAR();                                                                   \
    __asm__ volatile("s_waitcnt vmcnt(16)" ::: "memory");                     \
    __builtin_amdgcn_s_barrier();                                             \
    SBAR();                                                                   \
    { const int kn = ((KC) + 1 < 16) ? ((KC) + 1) : 15;                       \
      _Pragma("unroll")                                                       \
      for (int it = 0; it < 4; ++it) {                                        \
        int s = it * 256 + tid;                                               \
        dma16(Wt + ((size_t)2 * 16384 + (size_t)kn * 1024 + s) * 8,           \
              (char*)Ws[WBUF] + (it * 256 + wave * 64) * 16);                 \
      } }                                                                     \
    { const unsigned short* wb = Ws[RBUF];                                    \
      _Pragma("unroll")                                                       \
      for (int lo = 0; lo < 2; ++lo) {                                        \
        const int nrow = (wave * 2 + lo) * 16 + mm;                           \
        _Pragma("unroll")                                                     \
        for (int ks = 0; ks < 2; ++ks) {                                      \
          const int pp = (ks * 4 + quad) ^ (mm & 7);                          \
          bf16x8 bf = *(const bf16x8*)(wb + nrow * 64 + pp * 8);              \
          _Pragma("unroll")                                                   \
          for (int rt = 0; rt < 4; ++rt)                                      \
            acc[rt][lo] = mfma16(AFC[rt][ks], bf, acc[rt][lo]);               \
        }                                                                     \
      } }                                                                     \
    SBAR();                                                                   \
  }

__global__ __launch_bounds__(256, 2) void proj_v(
    const float* __restrict__ x, const unsigned short* __restrict__ Wt,
    unsigned short* __restrict__ Vz)
{
  __shared__ unsigned short Ws[2][128 * 64];
  const int tid = threadIdx.x;
  const int wave = tid >> 6, lane = tid & 63;
  const int quad = lane >> 4, mm = lane & 15;
  const int rb = blockIdx.x * 64;

  f32x4 acc[4][2];
  #pragma unroll
  for (int i = 0; i < 4; ++i) { acc[i][0] = f32x4{0.f,0.f,0.f,0.f}; acc[i][1] = f32x4{0.f,0.f,0.f,0.f}; }

  const float* ab[4];
  #pragma unroll
  for (int rt = 0; rt < 4; ++rt)
    ab[rt] = x + (size_t)(rb + rt * 16 + mm) * EM + quad * 8;

  f32x4 An[4][2][2];
  bf16x8 afA[4][2], afB[4][2];

  // ---- prologue ----
  #pragma unroll
  for (int rt = 0; rt < 4; ++rt)
    #pragma unroll
    for (int ks = 0; ks < 2; ++ks) {
      An[rt][ks][0] = *(const f32x4*)(ab[rt] + ks * 32);
      An[rt][ks][1] = *(const f32x4*)(ab[rt] + ks * 32 + 4);
    }
  #pragma unroll
  for (int rt = 0; rt < 4; ++rt)
    #pragma unroll
    for (int ks = 0; ks < 2; ++ks) afA[rt][ks] = cvt8(An[rt][ks][0], An[rt][ks][1]);
  SBAR();
  #pragma unroll
  for (int rt = 0; rt < 4; ++rt)
    #pragma unroll
    for (int ks = 0; ks < 2; ++ks) {
      An[rt][ks][0] = *(const f32x4*)(ab[rt] + 64 + ks * 32);
      An[rt][ks][1] = *(const f32x4*)(ab[rt] + 64 + ks * 32 + 4);
    }
  SBAR();
  #pragma unroll
  for (int it = 0; it < 4; ++it) {
    int s = it * 256 + tid;
    dma16(Wt + ((size_t)2 * 16384 + s) * 8,
          (char*)Ws[0] + (it * 256 + wave * 64) * 16);
  }
  SBAR();

  #pragma unroll 1
  for (int t = 0; t < 8; ++t) {
    const int kc = t * 2;
    V_STEP(kc,     afA, afB, 0, 1)
    V_STEP(kc + 1, afB, afA, 1, 0)
  }

  #pragma unroll
  for (int rt = 0; rt < 4; ++rt)
    #pragma unroll
    for (int lo = 0; lo < 2; ++lo) {
      const int d = (wave * 2 + lo) * 16 + mm;
      const int row0 = rb + rt * 16 + quad * 4;
      const int b = row0 >> 11, j0 = row0 & (SL - 1);
      u16x4 pk = u16x4{ f2bf(acc[rt][lo][0]), f2bf(acc[rt][lo][1]),
                        f2bf(acc[rt][lo][2]), f2bf(acc[rt][lo][3]) };
      size_t off = (size_t)b * DKD * SL + (size_t)d * SL + (j0 & ~63)
                 + ((((j0 >> 3) & 7) ^ (d & 7)) * 8) + (j0 & 7);
      *(u16x4*)(Vz + off) = pk;
    }
}

// ---------------------------------------------------------------------------
// attn: flash attention, 64 q-rows/block, pipelined 64-key blocks (dbuf DMA).
// Fully-padded query blocks (qb >= len) short-circuit to mean(V[0..len)).
// ---------------------------------------------------------------------------
__global__ __launch_bounds__(256, 2) void attn(
    const unsigned short* __restrict__ Qw, const unsigned short* __restrict__ Kz,
    const unsigned short* __restrict__ Vz, const int* __restrict__ lens,
    float* __restrict__ out)
{
  __shared__ unsigned short Ks[2][64 * 128];   // [j][16 chunks x 8], swz c^(j&15)
  __shared__ unsigned short Vs[2][128 * 64];   // [d][8 chunks x 8],  swz c^(d&7)
  __shared__ unsigned short Ps[4][16 * 72];    // per-wave P [q][j+pad8]
  __shared__ float mv[128];
  const int tid = threadIdx.x;
  const int wave = tid >> 6, lane = tid & 63;
  const int quad = lane >> 4, mm = lane & 15;
  const int b = blockIdx.y;
  const int qb = ((int)gridDim.x - 1 - (int)blockIdx.x) * 64;  // heavy blocks first
  const int len = lens[b];

  if (qb >= len) {
    // ---- mean-V path: every row in this block averages V[0..len) ----
    const int half = tid >> 7, d = tid & 127, d7 = d & 7;
    const unsigned short* vbase = Vz + (size_t)b * DKD * SL + (size_t)d * SL;
    float sum = 0.f;
    for (int j0 = half * 64; j0 < len; j0 += 128) {
      #pragma unroll
      for (int cc = 0; cc < 8; ++cc) {
        const int jstart = j0 + cc * 8;
        if (jstart >= len) break;
        const unsigned short* p = vbase + j0 + ((cc ^ d7) * 8);
        if (jstart + 8 <= len) {
          bf16x8 v = *(const bf16x8*)p;
          sum += (float)v[0] + (float)v[1] + (float)v[2] + (float)v[3]
               + (float)v[4] + (float)v[5] + (float)v[6] + (float)v[7];
        } else {
          for (int r = 0; r < 8; ++r)
            if (jstart + r < len) sum += (float)*(const __bf16*)(p + r);
        }
      }
    }
    if (half == 0) mv[d] = sum;
    __syncthreads();
    if (half == 1) mv[d] += sum;
    __syncthreads();
    const float val = mv[d] / (float)len;
    #pragma unroll 1
    for (int it = 0; it < 32; ++it) {
      const int row = qb + half + it * 2;
      out[((size_t)b * SL + row) * DKD + d] = val;
    }
    return;
  }

  const int kend = min(qb + 64, len);
  const int nblk = (kend + 63) >> 6;
  const int irow0 = qb + wave * 16 + quad * 4;

  bf16x8 aQ[4];
  {
    const unsigned short* qbase =
        Qw + (size_t)(b * SL + qb + wave * 16 + mm) * DKD + quad * 8;
    #pragma unroll
    for (int cc = 0; cc < 4; ++cc) aQ[cc] = *(const bf16x8*)(qbase + cc * 32);
  }
  float mr[4], lr[4];
  #pragma unroll
  for (int r = 0; r < 4; ++r) { mr[r] = -__builtin_inff(); lr[r] = 0.f; }
  f32x4 acc[8];
  #pragma unroll
  for (int i = 0; i < 8; ++i) acc[i] = f32x4{0.f,0.f,0.f,0.f};

  // prologue DMA: block 0 -> buf 0
  #pragma unroll
  for (int it = 0; it < 4; ++it) {
    int s = it * 256 + tid;
    dma16(Kz + (size_t)(b * SL) * DKD + (size_t)s * 8,
          (char*)Ks[0] + (it * 256 + wave * 64) * 16);
  }
  #pragma unroll
  for (int it = 0; it < 4; ++it) {
    int s = it * 256 + tid;
    int d = s >> 3, p = s & 7;
    dma16(Vz + (size_t)b * DKD * SL + (size_t)d * SL + p * 8,
          (char*)Vs[0] + (it * 256 + wave * 64) * 16);
  }

  #pragma unroll 1
  for (int blk = 0; blk < nblk; ++blk) {
    const int kb = blk * 64;
    __syncthreads();                       // drains DMA(blk)
    if (blk + 1 < nblk) {                  // issue next block's DMA
      const int kb1 = kb + 64;
      const int nb = (blk + 1) & 1;
      #pragma unroll
      for (int it = 0; it < 4; ++it) {
        int s = it * 256 + tid;
        dma16(Kz + (size_t)(b * SL + kb1) * DKD + (size_t)s * 8,
              (char*)Ks[nb] + (it * 256 + wave * 64) * 16);
      }
      #pragma unroll
      for (int it = 0; it < 4; ++it) {
        int s = it * 256 + tid;
        int d = s >> 3, p = s & 7;
        dma16(Vz + (size_t)b * DKD * SL + (size_t)d * SL + kb1 + p * 8,
              (char*)Vs[nb] + (it * 256 + wave * 64) * 16);
      }
    }
    const unsigned short* kbuf = Ks[blk & 1];
    const unsigned short* vbuf = Vs[blk & 1];

    // S = Q K^T : 4 key-tiles
    f32x4 s4[4];
    #pragma unroll
    for (int nt = 0; nt < 4; ++nt) {
      f32x4 c = f32x4{0.f,0.f,0.f,0.f};
      const int j = nt * 16 + mm;
      #pragma unroll
      for (int cc = 0; cc < 4; ++cc) {
        const int pp = (cc * 4 + quad) ^ mm;
        bf16x8 kf = *(const bf16x8*)(kbuf + j * 128 + pp * 8);
        c = mfma16(aQ[cc], kf, c);
      }
      s4[nt] = c;
    }

    float alpha[4];
    #pragma unroll
    for (int reg = 0; reg < 4; ++reg) {
      const int jl = min(irow0 + reg + 1, len);
      float v0 = (kb + mm      < jl) ? s4[0][reg] : -__builtin_inff();
      float v1 = (kb + 16 + mm < jl) ? s4[1][reg] : -__builtin_inff();
      float v2 = (kb + 32 + mm < jl) ? s4[2][reg] : -__builtin_inff();
      float v3 = (kb + 48 + mm < jl) ? s4[3][reg] : -__builtin_inff();
      float mx = fmaxf(fmaxf(v0, v1), fmaxf(v2, v3));
      #pragma unroll
      for (int xm = 1; xm < 16; xm <<= 1) mx = fmaxf(mx, __shfl_xor(mx, xm));
      const float mn = fmaxf(mr[reg], mx);
      alpha[reg] = __builtin_amdgcn_exp2f(mr[reg] - mn);
      const float p0 = __builtin_amdgcn_exp2f(v0 - mn);
      const float p1 = __builtin_amdgcn_exp2f(v1 - mn);
      const float p2 = __builtin_amdgcn_exp2f(v2 - mn);
      const float p3 = __builtin_amdgcn_exp2f(v3 - mn);
      float sm = (p0 + p1) + (p2 + p3);
      #pragma unroll
      for (int xm = 1; xm < 16; xm <<= 1) sm += __shfl_xor(sm, xm);
      lr[reg] = lr[reg] * alpha[reg] + sm;
      mr[reg] = mn;
      const int prow = quad * 4 + reg;
      Ps[wave][prow * 72 + mm]      = f2bf(p0);
      Ps[wave][prow * 72 + 16 + mm] = f2bf(p1);
      Ps[wave][prow * 72 + 32 + mm] = f2bf(p2);
      Ps[wave][prow * 72 + 48 + mm] = f2bf(p3);
    }
    #pragma unroll
    for (int nt = 0; nt < 8; ++nt) {
      f32x4 a = acc[nt];
      a[0] *= alpha[0]; a[1] *= alpha[1]; a[2] *= alpha[2]; a[3] *= alpha[3];
      acc[nt] = a;
    }
    __asm__ volatile("s_waitcnt lgkmcnt(0)" ::: "memory");  // P writes -> reads
    bf16x8 aP[2];
    #pragma unroll
    for (int ks = 0; ks < 2; ++ks)
      aP[ks] = *(const bf16x8*)(&Ps[wave][mm * 72 + ks * 32 + quad * 8]);
    #pragma unroll
    for (int ks = 0; ks < 2; ++ks)
      #pragma unroll
      for (int nt = 0; nt < 8; ++nt) {
        const int pp = (ks * 4 + quad) ^ (mm & 7);
        bf16x8 vf = *(const bf16x8*)(vbuf + (nt * 16 + mm) * 64 + pp * 8);
        acc[nt] = mfma16(aP[ks], vf, acc[nt]);
      }
  }

  #pragma unroll
  for (int reg = 0; reg < 4; ++reg) {
    const float rl = 1.0f / lr[reg];
    const size_t base = ((size_t)b * SL + irow0 + reg) * DKD + mm;
    #pragma unroll
    for (int nt = 0; nt < 8; ++nt)
      out[base + nt * 16] = acc[nt][reg] * rl;
  }
}

// ---------------------------------------------------------------------------
extern "C" void kernel_launch(void* const* d_in, const int* in_sizes, int n_in,
                              void* d_out, int out_size, void* d_ws, size_t ws_size,
                              hipStream_t stream) {
  const float* x    = (const float*)d_in[0];
  const float* ctx  = (const float*)d_in[1];
  const int*   lens = (const int*)d_in[2];
  const float* Wq   = (const float*)d_in[3];
  const float* Wk   = (const float*)d_in[4];
  const float* Wv   = (const float*)d_in[5];
  float* out = (float*)d_out;

  const size_t QKV = (size_t)NB * SL * DKD * sizeof(unsigned short); // 8 MiB each
  const size_t WTSZ = (size_t)3 * 16 * 128 * 8 * 8 * sizeof(unsigned short); // 768 KiB
  if (ws_size < 3 * QKV + WTSZ) return;
  unsigned short* Qws = (unsigned short*)d_ws;
  unsigned short* Kzs = (unsigned short*)((char*)d_ws + QKV);
  unsigned short* Vzs = (unsigned short*)((char*)d_ws + 2 * QKV);
  unsigned short* Wt  = (unsigned short*)((char*)d_ws + 3 * QKV);

  prep_w <<<dim3(48), 256, 0, stream>>>(Wq, Wk, Wv, Wt);
  proj_qk<<<dim3(NB * SL / 64), 256, 0, stream>>>(ctx, Wt, lens, Qws, Kzs);
  proj_v <<<dim3(NB * SL / 64), 256, 0, stream>>>(x, Wt, Vzs);
  attn   <<<dim3(SL / 64, NB), 256, 0, stream>>>(Qws, Kzs, Vzs, lens, out);
}

// Round 3
// 377.300 us; speedup vs baseline: 1.2826x; 1.2826x over previous
//
#include <hip/hip_runtime.h>

#define DEV __device__ __forceinline__

typedef __attribute__((ext_vector_type(4))) float f32x4;
typedef __attribute__((ext_vector_type(4))) unsigned short u16x4;
typedef __attribute__((ext_vector_type(8))) __bf16 bf16x8;

constexpr int NB = 16, SL = 2048, EM = 1024, DKD = 128;

DEV unsigned short f2bf(float f) {           // fp32 -> bf16 RNE
  unsigned int u = __float_as_uint(f);
  u += 0x7FFFu + ((u >> 16) & 1u);
  return (unsigned short)(u >> 16);
}

DEV f32x4 mfma16(bf16x8 a, bf16x8 b, f32x4 c) {
  return __builtin_amdgcn_mfma_f32_16x16x32_bf16(a, b, c, 0, 0, 0);
}

// async global->LDS DMA, 16B per lane; lds dst = wave-uniform base + lane*16
DEV void dma16(const void* g, void* l) {
  __builtin_amdgcn_global_load_lds(
      (const __attribute__((address_space(1))) unsigned int*)g,
      (__attribute__((address_space(3))) unsigned int*)l, 16, 0, 0);
}

DEV bf16x8 cvt8(f32x4 a, f32x4 b) {
  bf16x8 r;
  r[0] = (__bf16)a[0]; r[1] = (__bf16)a[1]; r[2] = (__bf16)a[2]; r[3] = (__bf16)a[3];
  r[4] = (__bf16)b[0]; r[5] = (__bf16)b[1]; r[6] = (__bf16)b[2]; r[7] = (__bf16)b[3];
  return r;
}

// ---------------------------------------------------------------------------
// prep_w: Wq/Wk/Wv fp32 [1024][128] -> bf16, tiled+swizzled, DMA-ready.
// Chunk t = ((m*16 + kc)*128 + n)*8 + p holds W_m[k = kc*64 + (p^(n&7))*8 + e][n].
// ---------------------------------------------------------------------------
__global__ __launch_bounds__(256) void prep_w(
    const float* __restrict__ Wq, const float* __restrict__ Wk,
    const float* __restrict__ Wv, unsigned short* __restrict__ Wt)
{
  __shared__ unsigned short T[64 * 128];     // [kk][n] bf16
  const int tid = threadIdx.x;
  const int m = blockIdx.x >> 4, kc = blockIdx.x & 15;   // 48 blocks
  const float* W = (m == 0) ? Wq : ((m == 1) ? Wk : Wv);
  #pragma unroll
  for (int it = 0; it < 8; ++it) {
    int idx = it * 256 + tid;                // 2048 f32x4 chunks
    int kk = idx >> 5, n4 = (idx & 31) * 4;
    f32x4 w4 = *(const f32x4*)(W + (size_t)(kc * 64 + kk) * DKD + n4);
    *(u16x4*)&T[kk * 128 + n4] =
        u16x4{ f2bf(w4[0]), f2bf(w4[1]), f2bf(w4[2]), f2bf(w4[3]) };
  }
  __syncthreads();
  #pragma unroll
  for (int it = 0; it < 4; ++it) {
    int idx = it * 256 + tid;                // 1024 out chunks, p fastest
    int p = idx & 7, n = idx >> 3;
    int c = p ^ (n & 7);
    unsigned short v[8];
    #pragma unroll
    for (int e = 0; e < 8; ++e) v[e] = T[(c * 8 + e) * 128 + n];
    size_t t = ((size_t)(m * 16 + kc) * 128 + n) * 8 + p;
    *(u16x4*)(Wt + t * 8)     = u16x4{v[0], v[1], v[2], v[3]};
    *(u16x4*)(Wt + t * 8 + 4) = u16x4{v[4], v[5], v[6], v[7]};
  }
}

// ---------------------------------------------------------------------------
// proj_qk: Q,K = ctx @ {Wq,Wk}. M-tile 64 (grid 512), N = 256 (Q|K).
// A-tile staged via global_load_lds with pre-swizzled per-lane SOURCE
// (dest linear; slot s of row r holds chunk c=(s&8)|((s&7)^(r&7)) — the
// read applies the same involution). Loads A once per block (was 4x, one
// copy per wave). No An register stage -> ~130 live VGPR, no spill.
//
// Per-iter schedule (counted waits, never a full mid-loop drain of W):
//   b: ds_read A(kc) + cvt -> af            [A ready per prev barrier#2]
//   c: s_waitcnt vmcnt(0) [only W(kc) x8 outstanding]; s_barrier  (#1)
//   d: issue A-DMA(kc+1) x4/wave  (safe: all waves past their A reads)
//   e: issue W-DMA(kc+1) x8/wave -> Ws[other]
//   f: MFMA(kc) on Ws[kc&1]                 [hides A(kc+1) latency]
//   g: s_waitcnt vmcnt(8) [A(kc+1) done; W(kc+1) rides on]; s_barrier (#2)
// Tail prefetches clamped (kn=15) so counts stay uniform; drained after loop.
// ---------------------------------------------------------------------------
__global__ __launch_bounds__(256, 2) void proj_qk(
    const float* __restrict__ ctx, const unsigned short* __restrict__ Wt,
    const int* __restrict__ lens, unsigned short* __restrict__ Qo,
    unsigned short* __restrict__ Kz)
{
  __shared__ unsigned short Ws[2][256 * 64];   // 64 KiB weight dbuf
  __shared__ float Als[64 * 64];               // 16 KiB A tile (single buf)
  const int tid = threadIdx.x;
  const int wave = tid >> 6, lane = tid & 63;
  const int quad = lane >> 4, mm = lane & 15;
  const int rb = blockIdx.x * 64;

  f32x4 acc[4][4];
  #pragma unroll
  for (int i = 0; i < 4; ++i)
    #pragma unroll
    for (int j = 0; j < 4; ++j) acc[i][j] = f32x4{0.f, 0.f, 0.f, 0.f};

  // A-DMA source pointers: instr i covers rows wave*16+i*4 + (lane>>4),
  // slot s=lane&15 sources logical chunk c=(s&8)|((s&7)^(row&7)).
  const float* asrc[4];
  #pragma unroll
  for (int i = 0; i < 4; ++i) {
    const int rl_ = wave * 16 + i * 4 + (lane >> 4);
    const int cc  = (lane & 8) | ((lane & 7) ^ (rl_ & 7));
    asrc[i] = ctx + (size_t)(rb + rl_) * EM + cc * 4;
  }
  // A-read float offsets within a row (64 floats/row), loop-invariant:
  // slot(ks,j) = ks*8 + ((quad*2+j) ^ (mm&7))
  int soff[2][2];
  #pragma unroll
  for (int ks = 0; ks < 2; ++ks) {
    soff[ks][0] = (ks * 8 + ((quad * 2)     ^ (mm & 7))) * 4;
    soff[ks][1] = (ks * 8 + ((quad * 2 + 1) ^ (mm & 7))) * 4;
  }

  // ---- prologue: A(0) x4, W(0) x8; wait A (W rides); barrier ----
  #pragma unroll
  for (int i = 0; i < 4; ++i)
    dma16(asrc[i], (char*)Als + wave * 4096 + i * 1024);
  #pragma unroll
  for (int it = 0; it < 8; ++it) {
    int s = it * 256 + tid;
    int mtx = s >> 10, sl = s & 1023;
    dma16(Wt + ((size_t)mtx * 16384 + sl) * 8,
          (char*)Ws[0] + (it * 256 + wave * 64) * 16);
  }
  __asm__ volatile("s_waitcnt vmcnt(8)" ::: "memory");
  __builtin_amdgcn_s_barrier();

  #pragma unroll 1
  for (int kc = 0; kc < 16; ++kc) {
    // b: A(kc) LDS -> af
    bf16x8 af[4][2];
    #pragma unroll
    for (int rt = 0; rt < 4; ++rt) {
      const float* rbase = Als + (rt * 16 + mm) * 64;
      #pragma unroll
      for (int ks = 0; ks < 2; ++ks) {
        f32x4 a0 = *(const f32x4*)(rbase + soff[ks][0]);
        f32x4 a1 = *(const f32x4*)(rbase + soff[ks][1]);
        af[rt][ks] = cvt8(a0, a1);
      }
    }
    // c: W(kc) arrival (only its 8 ops outstanding) + block-wide A-read fence
    __asm__ volatile("s_waitcnt vmcnt(0)" ::: "memory");
    __builtin_amdgcn_s_barrier();
    // d+e: prefetch kc+1 (clamped on tail to keep counts uniform)
    {
      const int kn = (kc + 1 < 16) ? (kc + 1) : 15;
      #pragma unroll
      for (int i = 0; i < 4; ++i)
        dma16(asrc[i] + kn * 64, (char*)Als + wave * 4096 + i * 1024);
      #pragma unroll
      for (int it = 0; it < 8; ++it) {
        int s = it * 256 + tid;
        int mtx = s >> 10, sl = s & 1023;
        dma16(Wt + ((size_t)mtx * 16384 + (size_t)kn * 1024 + sl) * 8,
              (char*)Ws[(kc + 1) & 1] + (it * 256 + wave * 64) * 16);
      }
    }
    // f: MFMA(kc)
    {
      const unsigned short* wb = Ws[kc & 1];
      #pragma unroll
      for (int lo = 0; lo < 4; ++lo) {
        const int nrow = (wave * 4 + lo) * 16 + mm;
        #pragma unroll
        for (int ks = 0; ks < 2; ++ks) {
          const int pp = (ks * 4 + quad) ^ (mm & 7);
          bf16x8 bf = *(const bf16x8*)(wb + nrow * 64 + pp * 8);
          #pragma unroll
          for (int rt = 0; rt < 4; ++rt)
            acc[rt][lo] = mfma16(af[rt][ks], bf, acc[rt][lo]);
        }
      }
    }
    // g: A(kc+1) landed (W(kc+1) x8 still in flight across the barrier)
    __asm__ volatile("s_waitcnt vmcnt(8)" ::: "memory");
    __builtin_amdgcn_s_barrier();
  }
  __asm__ volatile("s_waitcnt vmcnt(0)" ::: "memory");  // drain clamped tail

  const int len = lens[blockIdx.x >> 5];
  const float SCALE = 1.4426950408889634f * 0.08838834764831845f; // log2e/sqrt(128)
  #pragma unroll
  for (int rt = 0; rt < 4; ++rt)
    #pragma unroll
    for (int lo = 0; lo < 4; ++lo) {
      const int ctg = wave * 4 + lo;
      #pragma unroll
      for (int reg = 0; reg < 4; ++reg) {
        const int row = rb + rt * 16 + quad * 4 + reg;
        const int j = row & (SL - 1);
        const float val = acc[rt][lo][reg];
        if (ctg < 8) {
          const int d = ctg * 16 + mm;
          Qo[(size_t)row * DKD + d] = f2bf(val * ((j < len) ? SCALE : 0.f));
        } else {
          const int d = (ctg - 8) * 16 + mm;
          Kz[(size_t)row * DKD + (((d >> 3) ^ (j & 15)) * 8) + (d & 7)] = f2bf(val);
        }
      }
    }
}

// ---------------------------------------------------------------------------
// proj_v: V = x @ Wv, same schedule as proj_qk (W-DMA 4/wave, A-DMA 4/wave;
// waits: c=vmcnt(0) [4 W], g=vmcnt(4)). Output transposed+window-swizzled.
// ---------------------------------------------------------------------------
__global__ __launch_bounds__(256, 2) void proj_v(
    const float* __restrict__ x, const unsigned short* __restrict__ Wt,
    unsigned short* __restrict__ Vz)
{
  __shared__ unsigned short Ws[2][128 * 64];   // 32 KiB weight dbuf
  __shared__ float Als[64 * 64];               // 16 KiB A tile
  const int tid = threadIdx.x;
  const int wave = tid >> 6, lane = tid & 63;
  const int quad = lane >> 4, mm = lane & 15;
  const int rb = blockIdx.x * 64;

  f32x4 acc[4][2];
  #pragma unroll
  for (int i = 0; i < 4; ++i) { acc[i][0] = f32x4{0.f,0.f,0.f,0.f}; acc[i][1] = f32x4{0.f,0.f,0.f,0.f}; }

  const float* asrc[4];
  #pragma unroll
  for (int i = 0; i < 4; ++i) {
    const int rl_ = wave * 16 + i * 4 + (lane >> 4);
    const int cc  = (lane & 8) | ((lane & 7) ^ (rl_ & 7));
    asrc[i] = x + (size_t)(rb + rl_) * EM + cc * 4;
  }
  int soff[2][2];
  #pragma unroll
  for (int ks = 0; ks < 2; ++ks) {
    soff[ks][0] = (ks * 8 + ((quad * 2)     ^ (mm & 7))) * 4;
    soff[ks][1] = (ks * 8 + ((quad * 2 + 1) ^ (mm & 7))) * 4;
  }

  // ---- prologue ----
  #pragma unroll
  for (int i = 0; i < 4; ++i)
    dma16(asrc[i], (char*)Als + wave * 4096 + i * 1024);
  #pragma unroll
  for (int it = 0; it < 4; ++it) {
    int s = it * 256 + tid;
    dma16(Wt + ((size_t)2 * 16384 + s) * 8,
          (char*)Ws[0] + (it * 256 + wave * 64) * 16);
  }
  __asm__ volatile("s_waitcnt vmcnt(4)" ::: "memory");
  __builtin_amdgcn_s_barrier();

  #pragma unroll 1
  for (int kc = 0; kc < 16; ++kc) {
    bf16x8 af[4][2];
    #pragma unroll
    for (int rt = 0; rt < 4; ++rt) {
      const float* rbase = Als + (rt * 16 + mm) * 64;
      #pragma unroll
      for (int ks = 0; ks < 2; ++ks) {
        f32x4 a0 = *(const f32x4*)(rbase + soff[ks][0]);
        f32x4 a1 = *(const f32x4*)(rbase + soff[ks][1]);
        af[rt][ks] = cvt8(a0, a1);
      }
    }
    __asm__ volatile("s_waitcnt vmcnt(0)" ::: "memory");
    __builtin_amdgcn_s_barrier();
    {
      const int kn = (kc + 1 < 16) ? (kc + 1) : 15;
      #pragma unroll
      for (int i = 0; i < 4; ++i)
        dma16(asrc[i] + kn * 64, (char*)Als + wave * 4096 + i * 1024);
      #pragma unroll
      for (int it = 0; it < 4; ++it) {
        int s = it * 256 + tid;
        dma16(Wt + ((size_t)2 * 16384 + (size_t)kn * 1024 + s) * 8,
              (char*)Ws[(kc + 1) & 1] + (it * 256 + wave * 64) * 16);
      }
    }
    {
      const unsigned short* wb = Ws[kc & 1];
      #pragma unroll
      for (int lo = 0; lo < 2; ++lo) {
        const int nrow = (wave * 2 + lo) * 16 + mm;
        #pragma unroll
        for (int ks = 0; ks < 2; ++ks) {
          const int pp = (ks * 4 + quad) ^ (mm & 7);
          bf16x8 bf = *(const bf16x8*)(wb + nrow * 64 + pp * 8);
          #pragma unroll
          for (int rt = 0; rt < 4; ++rt)
            acc[rt][lo] = mfma16(af[rt][ks], bf, acc[rt][lo]);
        }
      }
    }
    __asm__ volatile("s_waitcnt vmcnt(4)" ::: "memory");
    __builtin_amdgcn_s_barrier();
  }
  __asm__ volatile("s_waitcnt vmcnt(0)" ::: "memory");

  #pragma unroll
  for (int rt = 0; rt < 4; ++rt)
    #pragma unroll
    for (int lo = 0; lo < 2; ++lo) {
      const int d = (wave * 2 + lo) * 16 + mm;
      const int row0 = rb + rt * 16 + quad * 4;
      const int b = row0 >> 11, j0 = row0 & (SL - 1);
      u16x4 pk = u16x4{ f2bf(acc[rt][lo][0]), f2bf(acc[rt][lo][1]),
                        f2bf(acc[rt][lo][2]), f2bf(acc[rt][lo][3]) };
      size_t off = (size_t)b * DKD * SL + (size_t)d * SL + (j0 & ~63)
                 + ((((j0 >> 3) & 7) ^ (d & 7)) * 8) + (j0 & 7);
      *(u16x4*)(Vz + off) = pk;
    }
}

// ---------------------------------------------------------------------------
// attn: flash attention, 64 q-rows/block, pipelined 64-key blocks (dbuf DMA).
// Fully-padded query blocks (qb >= len) short-circuit to mean(V[0..len)).
// ---------------------------------------------------------------------------
__global__ __launch_bounds__(256, 2) void attn(
    const unsigned short* __restrict__ Qw, const unsigned short* __restrict__ Kz,
    const unsigned short* __restrict__ Vz, const int* __restrict__ lens,
    float* __restrict__ out)
{
  __shared__ unsigned short Ks[2][64 * 128];   // [j][16 chunks x 8], swz c^(j&15)
  __shared__ unsigned short Vs[2][128 * 64];   // [d][8 chunks x 8],  swz c^(d&7)
  __shared__ unsigned short Ps[4][16 * 72];    // per-wave P [q][j+pad8]
  __shared__ float mv[128];
  const int tid = threadIdx.x;
  const int wave = tid >> 6, lane = tid & 63;
  const int quad = lane >> 4, mm = lane & 15;
  const int b = blockIdx.y;
  const int qb = ((int)gridDim.x - 1 - (int)blockIdx.x) * 64;  // heavy blocks first
  const int len = lens[b];

  if (qb >= len) {
    // ---- mean-V path: every row in this block averages V[0..len) ----
    const int half = tid >> 7, d = tid & 127, d7 = d & 7;
    const unsigned short* vbase = Vz + (size_t)b * DKD * SL + (size_t)d * SL;
    float sum = 0.f;
    for (int j0 = half * 64; j0 < len; j0 += 128) {
      #pragma unroll
      for (int cc = 0; cc < 8; ++cc) {
        const int jstart = j0 + cc * 8;
        if (jstart >= len) break;
        const unsigned short* p = vbase + j0 + ((cc ^ d7) * 8);
        if (jstart + 8 <= len) {
          bf16x8 v = *(const bf16x8*)p;
          sum += (float)v[0] + (float)v[1] + (float)v[2] + (float)v[3]
               + (float)v[4] + (float)v[5] + (float)v[6] + (float)v[7];
        } else {
          for (int r = 0; r < 8; ++r)
            if (jstart + r < len) sum += (float)*(const __bf16*)(p + r);
        }
      }
    }
    if (half == 0) mv[d] = sum;
    __syncthreads();
    if (half == 1) mv[d] += sum;
    __syncthreads();
    const float val = mv[d] / (float)len;
    #pragma unroll 1
    for (int it = 0; it < 32; ++it) {
      const int row = qb + half + it * 2;
      out[((size_t)b * SL + row) * DKD + d] = val;
    }
    return;
  }

  const int kend = min(qb + 64, len);
  const int nblk = (kend + 63) >> 6;
  const int irow0 = qb + wave * 16 + quad * 4;

  bf16x8 aQ[4];
  {
    const unsigned short* qbase =
        Qw + (size_t)(b * SL + qb + wave * 16 + mm) * DKD + quad * 8;
    #pragma unroll
    for (int cc = 0; cc < 4; ++cc) aQ[cc] = *(const bf16x8*)(qbase + cc * 32);
  }
  float mr[4], lr[4];
  #pragma unroll
  for (int r = 0; r < 4; ++r) { mr[r] = -__builtin_inff(); lr[r] = 0.f; }
  f32x4 acc[8];
  #pragma unroll
  for (int i = 0; i < 8; ++i) acc[i] = f32x4{0.f,0.f,0.f,0.f};

  // prologue DMA: block 0 -> buf 0
  #pragma unroll
  for (int it = 0; it < 4; ++it) {
    int s = it * 256 + tid;
    dma16(Kz + (size_t)(b * SL) * DKD + (size_t)s * 8,
          (char*)Ks[0] + (it * 256 + wave * 64) * 16);
  }
  #pragma unroll
  for (int it = 0; it < 4; ++it) {
    int s = it * 256 + tid;
    int d = s >> 3, p = s & 7;
    dma16(Vz + (size_t)b * DKD * SL + (size_t)d * SL + p * 8,
          (char*)Vs[0] + (it * 256 + wave * 64) * 16);
  }

  #pragma unroll 1
  for (int blk = 0; blk < nblk; ++blk) {
    const int kb = blk * 64;
    __syncthreads();                       // drains DMA(blk)
    if (blk + 1 < nblk) {                  // issue next block's DMA
      const int kb1 = kb + 64;
      const int nb = (blk + 1) & 1;
      #pragma unroll
      for (int it = 0; it < 4; ++it) {
        int s = it * 256 + tid;
        dma16(Kz + (size_t)(b * SL + kb1) * DKD + (size_t)s * 8,
              (char*)Ks[nb] + (it * 256 + wave * 64) * 16);
      }
      #pragma unroll
      for (int it = 0; it < 4; ++it) {
        int s = it * 256 + tid;
        int d = s >> 3, p = s & 7;
        dma16(Vz + (size_t)b * DKD * SL + (size_t)d * SL + kb1 + p * 8,
              (char*)Vs[nb] + (it * 256 + wave * 64) * 16);
      }
    }
    const unsigned short* kbuf = Ks[blk & 1];
    const unsigned short* vbuf = Vs[blk & 1];

    // S = Q K^T : 4 key-tiles
    f32x4 s4[4];
    #pragma unroll
    for (int nt = 0; nt < 4; ++nt) {
      f32x4 c = f32x4{0.f,0.f,0.f,0.f};
      const int j = nt * 16 + mm;
      #pragma unroll
      for (int cc = 0; cc < 4; ++cc) {
        const int pp = (cc * 4 + quad) ^ mm;
        bf16x8 kf = *(const bf16x8*)(kbuf + j * 128 + pp * 8);
        c = mfma16(aQ[cc], kf, c);
      }
      s4[nt] = c;
    }

    float alpha[4];
    #pragma unroll
    for (int reg = 0; reg < 4; ++reg) {
      const int jl = min(irow0 + reg + 1, len);
      float v0 = (kb + mm      < jl) ? s4[0][reg] : -__builtin_inff();
      float v1 = (kb + 16 + mm < jl) ? s4[1][reg] : -__builtin_inff();
      float v2 = (kb + 32 + mm < jl) ? s4[2][reg] : -__builtin_inff();
      float v3 = (kb + 48 + mm < jl) ? s4[3][reg] : -__builtin_inff();
      float mx = fmaxf(fmaxf(v0, v1), fmaxf(v2, v3));
      #pragma unroll
      for (int xm = 1; xm < 16; xm <<= 1) mx = fmaxf(mx, __shfl_xor(mx, xm));
      const float mn = fmaxf(mr[reg], mx);
      alpha[reg] = __builtin_amdgcn_exp2f(mr[reg] - mn);
      const float p0 = __builtin_amdgcn_exp2f(v0 - mn);
      const float p1 = __builtin_amdgcn_exp2f(v1 - mn);
      const float p2 = __builtin_amdgcn_exp2f(v2 - mn);
      const float p3 = __builtin_amdgcn_exp2f(v3 - mn);
      float sm = (p0 + p1) + (p2 + p3);
      #pragma unroll
      for (int xm = 1; xm < 16; xm <<= 1) sm += __shfl_xor(sm, xm);
      lr[reg] = lr[reg] * alpha[reg] + sm;
      mr[reg] = mn;
      const int prow = quad * 4 + reg;
      Ps[wave][prow * 72 + mm]      = f2bf(p0);
      Ps[wave][prow * 72 + 16 + mm] = f2bf(p1);
      Ps[wave][prow * 72 + 32 + mm] = f2bf(p2);
      Ps[wave][prow * 72 + 48 + mm] = f2bf(p3);
    }
    #pragma unroll
    for (int nt = 0; nt < 8; ++nt) {
      f32x4 a = acc[nt];
      a[0] *= alpha[0]; a[1] *= alpha[1]; a[2] *= alpha[2]; a[3] *= alpha[3];
      acc[nt] = a;
    }
    __asm__ volatile("s_waitcnt lgkmcnt(0)" ::: "memory");  // P writes -> reads
    bf16x8 aP[2];
    #pragma unroll
    for (int ks = 0; ks < 2; ++ks)
      aP[ks] = *(const bf16x8*)(&Ps[wave][mm * 72 + ks * 32 + quad * 8]);
    #pragma unroll
    for (int ks = 0; ks < 2; ++ks)
      #pragma unroll
      for (int nt = 0; nt < 8; ++nt) {
        const int pp = (ks * 4 + quad) ^ (mm & 7);
        bf16x8 vf = *(const bf16x8*)(vbuf + (nt * 16 + mm) * 64 + pp * 8);
        acc[nt] = mfma16(aP[ks], vf, acc[nt]);
      }
  }

  #pragma unroll
  for (int reg = 0; reg < 4; ++reg) {
    const float rl = 1.0f / lr[reg];
    const size_t base = ((size_t)b * SL + irow0 + reg) * DKD + mm;
    #pragma unroll
    for (int nt = 0; nt < 8; ++nt)
      out[base + nt * 16] = acc[nt][reg] * rl;
  }
}

// ---------------------------------------------------------------------------
extern "C" void kernel_launch(void* const* d_in, const int* in_sizes, int n_in,
                              void* d_out, int out_size, void* d_ws, size_t ws_size,
                              hipStream_t stream) {
  const float* x    = (const float*)d_in[0];
  const float* ctx  = (const float*)d_in[1];
  const int*   lens = (const int*)d_in[2];
  const float* Wq   = (const float*)d_in[3];
  const float* Wk   = (const float*)d_in[4];
  const float* Wv   = (const float*)d_in[5];
  float* out = (float*)d_out;

  const size_t QKV = (size_t)NB * SL * DKD * sizeof(unsigned short); // 8 MiB each
  const size_t WTSZ = (size_t)3 * 16 * 128 * 8 * 8 * sizeof(unsigned short); // 768 KiB
  if (ws_size < 3 * QKV + WTSZ) return;
  unsigned short* Qws = (unsigned short*)d_ws;
  unsigned short* Kzs = (unsigned short*)((char*)d_ws + QKV);
  unsigned short* Vzs = (unsigned short*)((char*)d_ws + 2 * QKV);
  unsigned short* Wt  = (unsigned short*)((char*)d_ws + 3 * QKV);

  prep_w <<<dim3(48), 256, 0, stream>>>(Wq, Wk, Wv, Wt);
  proj_qk<<<dim3(NB * SL / 64), 256, 0, stream>>>(ctx, Wt, lens, Qws, Kzs);
  proj_v <<<dim3(NB * SL / 64), 256, 0, stream>>>(x, Wt, Vzs);
  attn   <<<dim3(SL / 64, NB), 256, 0, stream>>>(Qws, Kzs, Vzs, lens, out);
}

// Round 4
// 353.439 us; speedup vs baseline: 1.3692x; 1.0675x over previous
//
#include <hip/hip_runtime.h>

#define DEV __device__ __forceinline__

typedef __attribute__((ext_vector_type(4))) float f32x4;
typedef __attribute__((ext_vector_type(4))) unsigned short u16x4;
typedef __attribute__((ext_vector_type(8))) __bf16 bf16x8;

constexpr int NB = 16, SL = 2048, EM = 1024, DKD = 128;

DEV unsigned short f2bf(float f) {           // fp32 -> bf16 RNE
  unsigned int u = __float_as_uint(f);
  u += 0x7FFFu + ((u >> 16) & 1u);
  return (unsigned short)(u >> 16);
}

DEV f32x4 mfma16(bf16x8 a, bf16x8 b, f32x4 c) {
  return __builtin_amdgcn_mfma_f32_16x16x32_bf16(a, b, c, 0, 0, 0);
}

// async global->LDS DMA, 16B per lane; lds dst = wave-uniform base + lane*16
DEV void dma16(const void* g, void* l) {
  __builtin_amdgcn_global_load_lds(
      (const __attribute__((address_space(1))) unsigned int*)g,
      (__attribute__((address_space(3))) unsigned int*)l, 16, 0, 0);
}

DEV bf16x8 cvt8(f32x4 a, f32x4 b) {
  bf16x8 r;
  r[0] = (__bf16)a[0]; r[1] = (__bf16)a[1]; r[2] = (__bf16)a[2]; r[3] = (__bf16)a[3];
  r[4] = (__bf16)b[0]; r[5] = (__bf16)b[1]; r[6] = (__bf16)b[2]; r[7] = (__bf16)b[3];
  return r;
}

#define SBAR() __builtin_amdgcn_sched_barrier(0)

// ---------------------------------------------------------------------------
// prep_w: Wq/Wk/Wv fp32 [1024][128] -> bf16, tiled+swizzled.
// Chunk t = ((m*16 + kc)*128 + n)*8 + p holds W_m[k = kc*64 + (p^(n&7))*8 + e][n].
// ---------------------------------------------------------------------------
__global__ __launch_bounds__(256) void prep_w(
    const float* __restrict__ Wq, const float* __restrict__ Wk,
    const float* __restrict__ Wv, unsigned short* __restrict__ Wt)
{
  __shared__ unsigned short T[64 * 128];     // [kk][n] bf16
  const int tid = threadIdx.x;
  const int m = blockIdx.x >> 4, kc = blockIdx.x & 15;   // 48 blocks
  const float* W = (m == 0) ? Wq : ((m == 1) ? Wk : Wv);
  #pragma unroll
  for (int it = 0; it < 8; ++it) {
    int idx = it * 256 + tid;                // 2048 f32x4 chunks
    int kk = idx >> 5, n4 = (idx & 31) * 4;
    f32x4 w4 = *(const f32x4*)(W + (size_t)(kc * 64 + kk) * DKD + n4);
    *(u16x4*)&T[kk * 128 + n4] =
        u16x4{ f2bf(w4[0]), f2bf(w4[1]), f2bf(w4[2]), f2bf(w4[3]) };
  }
  __syncthreads();
  #pragma unroll
  for (int it = 0; it < 4; ++it) {
    int idx = it * 256 + tid;                // 1024 out chunks, p fastest
    int p = idx & 7, n = idx >> 3;
    int c = p ^ (n & 7);
    unsigned short v[8];
    #pragma unroll
    for (int e = 0; e < 8; ++e) v[e] = T[(c * 8 + e) * 128 + n];
    size_t t = ((size_t)(m * 16 + kc) * 128 + n) * 8 + p;
    *(u16x4*)(Wt + t * 8)     = u16x4{v[0], v[1], v[2], v[3]};
    *(u16x4*)(Wt + t * 8 + 4) = u16x4{v[4], v[5], v[6], v[7]};
  }
}

// ---------------------------------------------------------------------------
// proj_qk: Q,K = ctx @ {Wq,Wk}. M-tile 64 (grid 512), N = 256 (Q|K).
//
// 1) Fully-padded blocks (local rb >= len) return immediately: attn only
//    reads Q/K rows < roundup(len,64), all produced by kept blocks.
// 2) A (HBM, ~900cy) double-buffered in LDS via global_load_lds, issued a
//    FULL iteration ahead. B/weights (L2-resident, ~200cy) loaded straight
//    to VGPRs from the pre-swizzled Wt each iter — no W LDS, no W barrier.
// Per iter: [SBAR pin] B(kc)->regs ; ds_read A(kc)+cvt ; lgkm0 ; barrier1 ;
//   issue A(kc+2)->Als[kc&1] ; MFMA (compiler's pre-MFMA vmcnt for B also
//   drains the older A(kc+1)) ; barrier2 (A(kc+1) visible to all).
// No manual vmcnt in the loop; nothing waits on just-issued ops.
// ---------------------------------------------------------------------------
__global__ __launch_bounds__(256, 2) void proj_qk(
    const float* __restrict__ ctx, const unsigned short* __restrict__ Wt,
    const int* __restrict__ lens, unsigned short* __restrict__ Qo,
    unsigned short* __restrict__ Kz)
{
  __shared__ float Als[2][64 * 64];            // 32 KiB A dbuf
  const int tid = threadIdx.x;
  const int wave = tid >> 6, lane = tid & 63;
  const int quad = lane >> 4, mm = lane & 15;
  const int rb = blockIdx.x * 64;
  const int len = lens[blockIdx.x >> 5];
  if ((rb & (SL - 1)) >= len) return;          // dead block: outputs never read

  f32x4 acc[4][4];
  #pragma unroll
  for (int i = 0; i < 4; ++i)
    #pragma unroll
    for (int j = 0; j < 4; ++j) acc[i][j] = f32x4{0.f, 0.f, 0.f, 0.f};

  // A-DMA source: instr i covers rows wave*16+i*4+(lane>>4); slot s=lane&15
  // sources chunk c=(s&8)|((s&7)^(row&7))  (involution, undone on read).
  const float* asrc[4];
  #pragma unroll
  for (int i = 0; i < 4; ++i) {
    const int rl_ = wave * 16 + i * 4 + (lane >> 4);
    const int cc  = (lane & 8) | ((lane & 7) ^ (rl_ & 7));
    asrc[i] = ctx + (size_t)(rb + rl_) * EM + cc * 4;
  }
  int soff[2][2];
  #pragma unroll
  for (int ks = 0; ks < 2; ++ks) {
    soff[ks][0] = (ks * 8 + ((quad * 2)     ^ (mm & 7))) * 4;
    soff[ks][1] = (ks * 8 + ((quad * 2 + 1) ^ (mm & 7))) * 4;
  }
  // B fragment global addresses (chunk cs of the DMA-order layout):
  // cs = nrow*8+pp ; global chunk = (cs>>10)*16384 + kc*1024 + (cs&1023)
  const unsigned short* bbase[4][2];
  #pragma unroll
  for (int lo = 0; lo < 4; ++lo)
    #pragma unroll
    for (int ks = 0; ks < 2; ++ks) {
      const int nrow = (wave * 4 + lo) * 16 + mm;
      const int pp = (ks * 4 + quad) ^ (mm & 7);
      const int cs = nrow * 8 + pp;
      bbase[lo][ks] = Wt + ((size_t)(cs >> 10) * 16384 + (cs & 1023)) * 8;
    }

  // ---- prologue: A(0)->Als[0], A(1)->Als[1]; wait A(0) (A(1) rides) ----
  #pragma unroll
  for (int i = 0; i < 4; ++i)
    dma16(asrc[i],      (char*)Als[0] + wave * 4096 + i * 1024);
  #pragma unroll
  for (int i = 0; i < 4; ++i)
    dma16(asrc[i] + 64, (char*)Als[1] + wave * 4096 + i * 1024);
  __asm__ volatile("s_waitcnt vmcnt(4)" ::: "memory");
  __builtin_amdgcn_s_barrier();

  #pragma unroll 1
  for (int kc = 0; kc < 16; ++kc) {
    SBAR();                                  // pin: nothing hoists into prev iter
    bf16x8 bfr[4][2];
    #pragma unroll
    for (int lo = 0; lo < 4; ++lo)
      #pragma unroll
      for (int ks = 0; ks < 2; ++ks)
        bfr[lo][ks] = *(const bf16x8*)(bbase[lo][ks] + (size_t)kc * 8192);
    bf16x8 af[4][2];
    #pragma unroll
    for (int rt = 0; rt < 4; ++rt) {
      const float* rbase = Als[kc & 1] + (rt * 16 + mm) * 64;
      #pragma unroll
      for (int ks = 0; ks < 2; ++ks) {
        f32x4 a0 = *(const f32x4*)(rbase + soff[ks][0]);
        f32x4 a1 = *(const f32x4*)(rbase + soff[ks][1]);
        af[rt][ks] = cvt8(a0, a1);
      }
    }
    __asm__ volatile("s_waitcnt lgkmcnt(0)" ::: "memory");  // A reads landed
    SBAR();
    __builtin_amdgcn_s_barrier();            // barrier1: safe to overwrite Als[kc&1]
    {
      const int kn = (kc + 2 < 16) ? (kc + 2) : 15;   // clamp tail
      #pragma unroll
      for (int i = 0; i < 4; ++i)
        dma16(asrc[i] + kn * 64, (char*)Als[kc & 1] + wave * 4096 + i * 1024);
    }
    #pragma unroll
    for (int lo = 0; lo < 4; ++lo)
      #pragma unroll
      for (int ks = 0; ks < 2; ++ks)
        #pragma unroll
        for (int rt = 0; rt < 4; ++rt)
          acc[rt][lo] = mfma16(af[rt][ks], bfr[lo][ks], acc[rt][lo]);
    __builtin_amdgcn_s_barrier();            // barrier2: A(kc+1) visible everywhere
  }
  __asm__ volatile("s_waitcnt vmcnt(0)" ::: "memory");   // drain clamped tail DMAs

  const float SCALE = 1.4426950408889634f * 0.08838834764831845f; // log2e/sqrt(128)
  #pragma unroll
  for (int rt = 0; rt < 4; ++rt)
    #pragma unroll
    for (int lo = 0; lo < 4; ++lo) {
      const int ctg = wave * 4 + lo;
      #pragma unroll
      for (int reg = 0; reg < 4; ++reg) {
        const int row = rb + rt * 16 + quad * 4 + reg;
        const int j = row & (SL - 1);
        const float val = acc[rt][lo][reg];
        if (ctg < 8) {
          const int d = ctg * 16 + mm;
          Qo[(size_t)row * DKD + d] = f2bf(val * ((j < len) ? SCALE : 0.f));
        } else {
          const int d = (ctg - 8) * 16 + mm;
          Kz[(size_t)row * DKD + (((d >> 3) ^ (j & 15)) * 8) + (d & 7)] = f2bf(val);
        }
      }
    }
}

// ---------------------------------------------------------------------------
// proj_v: V = x @ Wv, same structure as proj_qk (B direct from L2, A dbuf,
// dead-block skip). Output transposed+window-swizzled Vz[b][d][j-windows].
// ---------------------------------------------------------------------------
__global__ __launch_bounds__(256, 2) void proj_v(
    const float* __restrict__ x, const unsigned short* __restrict__ Wt,
    const int* __restrict__ lens, unsigned short* __restrict__ Vz)
{
  __shared__ float Als[2][64 * 64];            // 32 KiB A dbuf
  const int tid = threadIdx.x;
  const int wave = tid >> 6, lane = tid & 63;
  const int quad = lane >> 4, mm = lane & 15;
  const int rb = blockIdx.x * 64;
  const int len = lens[blockIdx.x >> 5];
  if ((rb & (SL - 1)) >= len) return;          // dead block: outputs never read

  f32x4 acc[4][2];
  #pragma unroll
  for (int i = 0; i < 4; ++i) { acc[i][0] = f32x4{0.f,0.f,0.f,0.f}; acc[i][1] = f32x4{0.f,0.f,0.f,0.f}; }

  const float* asrc[4];
  #pragma unroll
  for (int i = 0; i < 4; ++i) {
    const int rl_ = wave * 16 + i * 4 + (lane >> 4);
    const int cc  = (lane & 8) | ((lane & 7) ^ (rl_ & 7));
    asrc[i] = x + (size_t)(rb + rl_) * EM + cc * 4;
  }
  int soff[2][2];
  #pragma unroll
  for (int ks = 0; ks < 2; ++ks) {
    soff[ks][0] = (ks * 8 + ((quad * 2)     ^ (mm & 7))) * 4;
    soff[ks][1] = (ks * 8 + ((quad * 2 + 1) ^ (mm & 7))) * 4;
  }
  const unsigned short* bbase[2][2];
  #pragma unroll
  for (int lo = 0; lo < 2; ++lo)
    #pragma unroll
    for (int ks = 0; ks < 2; ++ks) {
      const int nrow = (wave * 2 + lo) * 16 + mm;
      const int pp = (ks * 4 + quad) ^ (mm & 7);
      const int cs = nrow * 8 + pp;            // cs < 1024
      bbase[lo][ks] = Wt + ((size_t)2 * 16384 + cs) * 8;
    }

  #pragma unroll
  for (int i = 0; i < 4; ++i)
    dma16(asrc[i],      (char*)Als[0] + wave * 4096 + i * 1024);
  #pragma unroll
  for (int i = 0; i < 4; ++i)
    dma16(asrc[i] + 64, (char*)Als[1] + wave * 4096 + i * 1024);
  __asm__ volatile("s_waitcnt vmcnt(4)" ::: "memory");
  __builtin_amdgcn_s_barrier();

  #pragma unroll 1
  for (int kc = 0; kc < 16; ++kc) {
    SBAR();
    bf16x8 bfr[2][2];
    #pragma unroll
    for (int lo = 0; lo < 2; ++lo)
      #pragma unroll
      for (int ks = 0; ks < 2; ++ks)
        bfr[lo][ks] = *(const bf16x8*)(bbase[lo][ks] + (size_t)kc * 8192);
    bf16x8 af[4][2];
    #pragma unroll
    for (int rt = 0; rt < 4; ++rt) {
      const float* rbase = Als[kc & 1] + (rt * 16 + mm) * 64;
      #pragma unroll
      for (int ks = 0; ks < 2; ++ks) {
        f32x4 a0 = *(const f32x4*)(rbase + soff[ks][0]);
        f32x4 a1 = *(const f32x4*)(rbase + soff[ks][1]);
        af[rt][ks] = cvt8(a0, a1);
      }
    }
    __asm__ volatile("s_waitcnt lgkmcnt(0)" ::: "memory");
    SBAR();
    __builtin_amdgcn_s_barrier();
    {
      const int kn = (kc + 2 < 16) ? (kc + 2) : 15;
      #pragma unroll
      for (int i = 0; i < 4; ++i)
        dma16(asrc[i] + kn * 64, (char*)Als[kc & 1] + wave * 4096 + i * 1024);
    }
    #pragma unroll
    for (int lo = 0; lo < 2; ++lo)
      #pragma unroll
      for (int ks = 0; ks < 2; ++ks)
        #pragma unroll
        for (int rt = 0; rt < 4; ++rt)
          acc[rt][lo] = mfma16(af[rt][ks], bfr[lo][ks], acc[rt][lo]);
    __builtin_amdgcn_s_barrier();
  }
  __asm__ volatile("s_waitcnt vmcnt(0)" ::: "memory");

  #pragma unroll
  for (int rt = 0; rt < 4; ++rt)
    #pragma unroll
    for (int lo = 0; lo < 2; ++lo) {
      const int d = (wave * 2 + lo) * 16 + mm;
      const int row0 = rb + rt * 16 + quad * 4;
      const int b = row0 >> 11, j0 = row0 & (SL - 1);
      u16x4 pk = u16x4{ f2bf(acc[rt][lo][0]), f2bf(acc[rt][lo][1]),
                        f2bf(acc[rt][lo][2]), f2bf(acc[rt][lo][3]) };
      size_t off = (size_t)b * DKD * SL + (size_t)d * SL + (j0 & ~63)
                 + ((((j0 >> 3) & 7) ^ (d & 7)) * 8) + (j0 & 7);
      *(u16x4*)(Vz + off) = pk;
    }
}

// ---------------------------------------------------------------------------
// attn: flash attention, 64 q-rows/block, pipelined 64-key blocks (dbuf DMA).
// Fully-padded query blocks (qb >= len) short-circuit to mean(V[0..len)).
// ---------------------------------------------------------------------------
__global__ __launch_bounds__(256, 2) void attn(
    const unsigned short* __restrict__ Qw, const unsigned short* __restrict__ Kz,
    const unsigned short* __restrict__ Vz, const int* __restrict__ lens,
    float* __restrict__ out)
{
  __shared__ unsigned short Ks[2][64 * 128];   // [j][16 chunks x 8], swz c^(j&15)
  __shared__ unsigned short Vs[2][128 * 64];   // [d][8 chunks x 8],  swz c^(d&7)
  __shared__ unsigned short Ps[4][16 * 72];    // per-wave P [q][j+pad8]
  __shared__ float mv[128];
  const int tid = threadIdx.x;
  const int wave = tid >> 6, lane = tid & 63;
  const int quad = lane >> 4, mm = lane & 15;
  const int b = blockIdx.y;
  const int qb = ((int)gridDim.x - 1 - (int)blockIdx.x) * 64;  // heavy blocks first
  const int len = lens[b];

  if (qb >= len) {
    // ---- mean-V path: every row in this block averages V[0..len) ----
    const int half = tid >> 7, d = tid & 127, d7 = d & 7;
    const unsigned short* vbase = Vz + (size_t)b * DKD * SL + (size_t)d * SL;
    float sum = 0.f;
    for (int j0 = half * 64; j0 < len; j0 += 128) {
      #pragma unroll
      for (int cc = 0; cc < 8; ++cc) {
        const int jstart = j0 + cc * 8;
        if (jstart >= len) break;
        const unsigned short* p = vbase + j0 + ((cc ^ d7) * 8);
        if (jstart + 8 <= len) {
          bf16x8 v = *(const bf16x8*)p;
          sum += (float)v[0] + (float)v[1] + (float)v[2] + (float)v[3]
               + (float)v[4] + (float)v[5] + (float)v[6] + (float)v[7];
        } else {
          for (int r = 0; r < 8; ++r)
            if (jstart + r < len) sum += (float)*(const __bf16*)(p + r);
        }
      }
    }
    if (half == 0) mv[d] = sum;
    __syncthreads();
    if (half == 1) mv[d] += sum;
    __syncthreads();
    const float val = mv[d] / (float)len;
    #pragma unroll 1
    for (int it = 0; it < 32; ++it) {
      const int row = qb + half + it * 2;
      out[((size_t)b * SL + row) * DKD + d] = val;
    }
    return;
  }

  const int kend = min(qb + 64, len);
  const int nblk = (kend + 63) >> 6;
  const int irow0 = qb + wave * 16 + quad * 4;

  bf16x8 aQ[4];
  {
    const unsigned short* qbase =
        Qw + (size_t)(b * SL + qb + wave * 16 + mm) * DKD + quad * 8;
    #pragma unroll
    for (int cc = 0; cc < 4; ++cc) aQ[cc] = *(const bf16x8*)(qbase + cc * 32);
  }
  float mr[4], lr[4];
  #pragma unroll
  for (int r = 0; r < 4; ++r) { mr[r] = -__builtin_inff(); lr[r] = 0.f; }
  f32x4 acc[8];
  #pragma unroll
  for (int i = 0; i < 8; ++i) acc[i] = f32x4{0.f,0.f,0.f,0.f};

  // prologue DMA: block 0 -> buf 0
  #pragma unroll
  for (int it = 0; it < 4; ++it) {
    int s = it * 256 + tid;
    dma16(Kz + (size_t)(b * SL) * DKD + (size_t)s * 8,
          (char*)Ks[0] + (it * 256 + wave * 64) * 16);
  }
  #pragma unroll
  for (int it = 0; it < 4; ++it) {
    int s = it * 256 + tid;
    int d = s >> 3, p = s & 7;
    dma16(Vz + (size_t)b * DKD * SL + (size_t)d * SL + p * 8,
          (char*)Vs[0] + (it * 256 + wave * 64) * 16);
  }

  #pragma unroll 1
  for (int blk = 0; blk < nblk; ++blk) {
    const int kb = blk * 64;
    __syncthreads();                       // drains DMA(blk)
    if (blk + 1 < nblk) {                  // issue next block's DMA
      const int kb1 = kb + 64;
      const int nb = (blk + 1) & 1;
      #pragma unroll
      for (int it = 0; it < 4; ++it) {
        int s = it * 256 + tid;
        dma16(Kz + (size_t)(b * SL + kb1) * DKD + (size_t)s * 8,
              (char*)Ks[nb] + (it * 256 + wave * 64) * 16);
      }
      #pragma unroll
      for (int it = 0; it < 4; ++it) {
        int s = it * 256 + tid;
        int d = s >> 3, p = s & 7;
        dma16(Vz + (size_t)b * DKD * SL + (size_t)d * SL + kb1 + p * 8,
              (char*)Vs[nb] + (it * 256 + wave * 64) * 16);
      }
    }
    const unsigned short* kbuf = Ks[blk & 1];
    const unsigned short* vbuf = Vs[blk & 1];

    // S = Q K^T : 4 key-tiles
    f32x4 s4[4];
    #pragma unroll
    for (int nt = 0; nt < 4; ++nt) {
      f32x4 c = f32x4{0.f,0.f,0.f,0.f};
      const int j = nt * 16 + mm;
      #pragma unroll
      for (int cc = 0; cc < 4; ++cc) {
        const int pp = (cc * 4 + quad) ^ mm;
        bf16x8 kf = *(const bf16x8*)(kbuf + j * 128 + pp * 8);
        c = mfma16(aQ[cc], kf, c);
      }
      s4[nt] = c;
    }

    float alpha[4];
    #pragma unroll
    for (int reg = 0; reg < 4; ++reg) {
      const int jl = min(irow0 + reg + 1, len);
      float v0 = (kb + mm      < jl) ? s4[0][reg] : -__builtin_inff();
      float v1 = (kb + 16 + mm < jl) ? s4[1][reg] : -__builtin_inff();
      float v2 = (kb + 32 + mm < jl) ? s4[2][reg] : -__builtin_inff();
      float v3 = (kb + 48 + mm < jl) ? s4[3][reg] : -__builtin_inff();
      float mx = fmaxf(fmaxf(v0, v1), fmaxf(v2, v3));
      #pragma unroll
      for (int xm = 1; xm < 16; xm <<= 1) mx = fmaxf(mx, __shfl_xor(mx, xm));
      const float mn = fmaxf(mr[reg], mx);
      alpha[reg] = __builtin_amdgcn_exp2f(mr[reg] - mn);
      const float p0 = __builtin_amdgcn_exp2f(v0 - mn);
      const float p1 = __builtin_amdgcn_exp2f(v1 - mn);
      const float p2 = __builtin_amdgcn_exp2f(v2 - mn);
      const float p3 = __builtin_amdgcn_exp2f(v3 - mn);
      float sm = (p0 + p1) + (p2 + p3);
      #pragma unroll
      for (int xm = 1; xm < 16; xm <<= 1) sm += __shfl_xor(sm, xm);
      lr[reg] = lr[reg] * alpha[reg] + sm;
      mr[reg] = mn;
      const int prow = quad * 4 + reg;
      Ps[wave][prow * 72 + mm]      = f2bf(p0);
      Ps[wave][prow * 72 + 16 + mm] = f2bf(p1);
      Ps[wave][prow * 72 + 32 + mm] = f2bf(p2);
      Ps[wave][prow * 72 + 48 + mm] = f2bf(p3);
    }
    #pragma unroll
    for (int nt = 0; nt < 8; ++nt) {
      f32x4 a = acc[nt];
      a[0] *= alpha[0]; a[1] *= alpha[1]; a[2] *= alpha[2]; a[3] *= alpha[3];
      acc[nt] = a;
    }
    __asm__ volatile("s_waitcnt lgkmcnt(0)" ::: "memory");  // P writes -> reads
    bf16x8 aP[2];
    #pragma unroll
    for (int ks = 0; ks < 2; ++ks)
      aP[ks] = *(const bf16x8*)(&Ps[wave][mm * 72 + ks * 32 + quad * 8]);
    #pragma unroll
    for (int ks = 0; ks < 2; ++ks)
      #pragma unroll
      for (int nt = 0; nt < 8; ++nt) {
        const int pp = (ks * 4 + quad) ^ (mm & 7);
        bf16x8 vf = *(const bf16x8*)(vbuf + (nt * 16 + mm) * 64 + pp * 8);
        acc[nt] = mfma16(aP[ks], vf, acc[nt]);
      }
  }

  #pragma unroll
  for (int reg = 0; reg < 4; ++reg) {
    const float rl = 1.0f / lr[reg];
    const size_t base = ((size_t)b * SL + irow0 + reg) * DKD + mm;
    #pragma unroll
    for (int nt = 0; nt < 8; ++nt)
      out[base + nt * 16] = acc[nt][reg] * rl;
  }
}

// ---------------------------------------------------------------------------
extern "C" void kernel_launch(void* const* d_in, const int* in_sizes, int n_in,
                              void* d_out, int out_size, void* d_ws, size_t ws_size,
                              hipStream_t stream) {
  const float* x    = (const float*)d_in[0];
  const float* ctx  = (const float*)d_in[1];
  const int*   lens = (const int*)d_in[2];
  const float* Wq   = (const float*)d_in[3];
  const float* Wk   = (const float*)d_in[4];
  const float* Wv   = (const float*)d_in[5];
  float* out = (float*)d_out;

  const size_t QKV = (size_t)NB * SL * DKD * sizeof(unsigned short); // 8 MiB each
  const size_t WTSZ = (size_t)3 * 16 * 128 * 8 * 8 * sizeof(unsigned short); // 768 KiB
  if (ws_size < 3 * QKV + WTSZ) return;
  unsigned short* Qws = (unsigned short*)d_ws;
  unsigned short* Kzs = (unsigned short*)((char*)d_ws + QKV);
  unsigned short* Vzs = (unsigned short*)((char*)d_ws + 2 * QKV);
  unsigned short* Wt  = (unsigned short*)((char*)d_ws + 3 * QKV);

  prep_w <<<dim3(48), 256, 0, stream>>>(Wq, Wk, Wv, Wt);
  proj_qk<<<dim3(NB * SL / 64), 256, 0, stream>>>(ctx, Wt, lens, Qws, Kzs);
  proj_v <<<dim3(NB * SL / 64), 256, 0, stream>>>(x, Wt, lens, Vzs);
  attn   <<<dim3(SL / 64, NB), 256, 0, stream>>>(Qws, Kzs, Vzs, lens, out);
}

// Round 5
// 346.849 us; speedup vs baseline: 1.3952x; 1.0190x over previous
//
#include <hip/hip_runtime.h>

#define DEV __device__ __forceinline__

typedef __attribute__((ext_vector_type(4))) float f32x4;
typedef __attribute__((ext_vector_type(4))) unsigned short u16x4;
typedef __attribute__((ext_vector_type(8))) __bf16 bf16x8;

constexpr int NB = 16, SL = 2048, EM = 1024, DKD = 128;

DEV unsigned short f2bf(float f) {           // fp32 -> bf16 RNE
  unsigned int u = __float_as_uint(f);
  u += 0x7FFFu + ((u >> 16) & 1u);
  return (unsigned short)(u >> 16);
}

DEV f32x4 mfma16(bf16x8 a, bf16x8 b, f32x4 c) {
  return __builtin_amdgcn_mfma_f32_16x16x32_bf16(a, b, c, 0, 0, 0);
}

// async global->LDS DMA, 16B per lane; lds dst = wave-uniform base + lane*16
DEV void dma16(const void* g, void* l) {
  __builtin_amdgcn_global_load_lds(
      (const __attribute__((address_space(1))) unsigned int*)g,
      (__attribute__((address_space(3))) unsigned int*)l, 16, 0, 0);
}

DEV bf16x8 cvt8(f32x4 a, f32x4 b) {
  bf16x8 r;
  r[0] = (__bf16)a[0]; r[1] = (__bf16)a[1]; r[2] = (__bf16)a[2]; r[3] = (__bf16)a[3];
  r[4] = (__bf16)b[0]; r[5] = (__bf16)b[1]; r[6] = (__bf16)b[2]; r[7] = (__bf16)b[3];
  return r;
}

#define SBAR() __builtin_amdgcn_sched_barrier(0)

// ---------------------------------------------------------------------------
// prep_w: Wq/Wk/Wv fp32 [1024][128] -> bf16, tiled+swizzled. Block 0 also
// zeroes the mean-V accumulator mvg[NB][128] (proj_v atomically adds into it;
// stream order makes the zero visible before proj_v runs).
// Chunk t = ((m*16 + kc)*128 + n)*8 + p holds W_m[k = kc*64 + (p^(n&7))*8 + e][n].
// ---------------------------------------------------------------------------
__global__ __launch_bounds__(256) void prep_w(
    const float* __restrict__ Wq, const float* __restrict__ Wk,
    const float* __restrict__ Wv, unsigned short* __restrict__ Wt,
    float* __restrict__ mvg)
{
  __shared__ unsigned short T[64 * 128];     // [kk][n] bf16
  const int tid = threadIdx.x;
  if (blockIdx.x == 0) {
    #pragma unroll
    for (int i = 0; i < NB * DKD / 256; ++i) mvg[i * 256 + tid] = 0.f;
  }
  const int m = blockIdx.x >> 4, kc = blockIdx.x & 15;   // 48 blocks
  const float* W = (m == 0) ? Wq : ((m == 1) ? Wk : Wv);
  #pragma unroll
  for (int it = 0; it < 8; ++it) {
    int idx = it * 256 + tid;                // 2048 f32x4 chunks
    int kk = idx >> 5, n4 = (idx & 31) * 4;
    f32x4 w4 = *(const f32x4*)(W + (size_t)(kc * 64 + kk) * DKD + n4);
    *(u16x4*)&T[kk * 128 + n4] =
        u16x4{ f2bf(w4[0]), f2bf(w4[1]), f2bf(w4[2]), f2bf(w4[3]) };
  }
  __syncthreads();
  #pragma unroll
  for (int it = 0; it < 4; ++it) {
    int idx = it * 256 + tid;                // 1024 out chunks, p fastest
    int p = idx & 7, n = idx >> 3;
    int c = p ^ (n & 7);
    unsigned short v[8];
    #pragma unroll
    for (int e = 0; e < 8; ++e) v[e] = T[(c * 8 + e) * 128 + n];
    size_t t = ((size_t)(m * 16 + kc) * 128 + n) * 8 + p;
    *(u16x4*)(Wt + t * 8)     = u16x4{v[0], v[1], v[2], v[3]};
    *(u16x4*)(Wt + t * 8 + 4) = u16x4{v[4], v[5], v[6], v[7]};
  }
}

// ---------------------------------------------------------------------------
// proj_qk: Q,K = ctx @ {Wq,Wk}. M-tile 64 (grid 512), N = 256 (Q|K).
// Dead blocks (rb >= len) return; A dbuf'd in LDS (full-iter prefetch);
// B straight from L2-resident pre-swizzled Wt.
// ---------------------------------------------------------------------------
__global__ __launch_bounds__(256, 2) void proj_qk(
    const float* __restrict__ ctx, const unsigned short* __restrict__ Wt,
    const int* __restrict__ lens, unsigned short* __restrict__ Qo,
    unsigned short* __restrict__ Kz)
{
  __shared__ float Als[2][64 * 64];            // 32 KiB A dbuf
  const int tid = threadIdx.x;
  const int wave = tid >> 6, lane = tid & 63;
  const int quad = lane >> 4, mm = lane & 15;
  const int rb = blockIdx.x * 64;
  const int len = lens[blockIdx.x >> 5];
  if ((rb & (SL - 1)) >= len) return;          // dead block: outputs never read

  f32x4 acc[4][4];
  #pragma unroll
  for (int i = 0; i < 4; ++i)
    #pragma unroll
    for (int j = 0; j < 4; ++j) acc[i][j] = f32x4{0.f, 0.f, 0.f, 0.f};

  // A-DMA source: instr i covers rows wave*16+i*4+(lane>>4); slot s=lane&15
  // sources chunk c=(s&8)|((s&7)^(row&7))  (involution, undone on read).
  const float* asrc[4];
  #pragma unroll
  for (int i = 0; i < 4; ++i) {
    const int rl_ = wave * 16 + i * 4 + (lane >> 4);
    const int cc  = (lane & 8) | ((lane & 7) ^ (rl_ & 7));
    asrc[i] = ctx + (size_t)(rb + rl_) * EM + cc * 4;
  }
  int soff[2][2];
  #pragma unroll
  for (int ks = 0; ks < 2; ++ks) {
    soff[ks][0] = (ks * 8 + ((quad * 2)     ^ (mm & 7))) * 4;
    soff[ks][1] = (ks * 8 + ((quad * 2 + 1) ^ (mm & 7))) * 4;
  }
  // B fragment global addresses (chunk cs of the DMA-order layout)
  const unsigned short* bbase[4][2];
  #pragma unroll
  for (int lo = 0; lo < 4; ++lo)
    #pragma unroll
    for (int ks = 0; ks < 2; ++ks) {
      const int nrow = (wave * 4 + lo) * 16 + mm;
      const int pp = (ks * 4 + quad) ^ (mm & 7);
      const int cs = nrow * 8 + pp;
      bbase[lo][ks] = Wt + ((size_t)(cs >> 10) * 16384 + (cs & 1023)) * 8;
    }

  #pragma unroll
  for (int i = 0; i < 4; ++i)
    dma16(asrc[i],      (char*)Als[0] + wave * 4096 + i * 1024);
  #pragma unroll
  for (int i = 0; i < 4; ++i)
    dma16(asrc[i] + 64, (char*)Als[1] + wave * 4096 + i * 1024);
  __asm__ volatile("s_waitcnt vmcnt(4)" ::: "memory");
  __builtin_amdgcn_s_barrier();

  #pragma unroll 1
  for (int kc = 0; kc < 16; ++kc) {
    SBAR();                                  // pin: nothing hoists into prev iter
    bf16x8 bfr[4][2];
    #pragma unroll
    for (int lo = 0; lo < 4; ++lo)
      #pragma unroll
      for (int ks = 0; ks < 2; ++ks)
        bfr[lo][ks] = *(const bf16x8*)(bbase[lo][ks] + (size_t)kc * 8192);
    bf16x8 af[4][2];
    #pragma unroll
    for (int rt = 0; rt < 4; ++rt) {
      const float* rbase = Als[kc & 1] + (rt * 16 + mm) * 64;
      #pragma unroll
      for (int ks = 0; ks < 2; ++ks) {
        f32x4 a0 = *(const f32x4*)(rbase + soff[ks][0]);
        f32x4 a1 = *(const f32x4*)(rbase + soff[ks][1]);
        af[rt][ks] = cvt8(a0, a1);
      }
    }
    __asm__ volatile("s_waitcnt lgkmcnt(0)" ::: "memory");  // A reads landed
    SBAR();
    __builtin_amdgcn_s_barrier();            // safe to overwrite Als[kc&1]
    {
      const int kn = (kc + 2 < 16) ? (kc + 2) : 15;   // clamp tail
      #pragma unroll
      for (int i = 0; i < 4; ++i)
        dma16(asrc[i] + kn * 64, (char*)Als[kc & 1] + wave * 4096 + i * 1024);
    }
    #pragma unroll
    for (int lo = 0; lo < 4; ++lo)
      #pragma unroll
      for (int ks = 0; ks < 2; ++ks)
        #pragma unroll
        for (int rt = 0; rt < 4; ++rt)
          acc[rt][lo] = mfma16(af[rt][ks], bfr[lo][ks], acc[rt][lo]);
    __builtin_amdgcn_s_barrier();            // A(kc+1) visible everywhere
  }
  __asm__ volatile("s_waitcnt vmcnt(0)" ::: "memory");   // drain clamped tail DMAs

  const float SCALE = 1.4426950408889634f * 0.08838834764831845f; // log2e/sqrt(128)
  #pragma unroll
  for (int rt = 0; rt < 4; ++rt)
    #pragma unroll
    for (int lo = 0; lo < 4; ++lo) {
      const int ctg = wave * 4 + lo;
      #pragma unroll
      for (int reg = 0; reg < 4; ++reg) {
        const int row = rb + rt * 16 + quad * 4 + reg;
        const int j = row & (SL - 1);
        const float val = acc[rt][lo][reg];
        if (ctg < 8) {
          const int d = ctg * 16 + mm;
          Qo[(size_t)row * DKD + d] = f2bf(val * ((j < len) ? SCALE : 0.f));
        } else {
          const int d = (ctg - 8) * 16 + mm;
          Kz[(size_t)row * DKD + (((d >> 3) ^ (j & 15)) * 8) + (d & 7)] = f2bf(val);
        }
      }
    }
}

// ---------------------------------------------------------------------------
// proj_v: V = x @ Wv (same structure). Epilogue additionally accumulates the
// per-batch column-sum of V over valid rows (j < len) into mvg[b][d] via one
// atomicAdd per (d, block) after a cross-quad shfl reduce — feeds attn's
// dead-block mean path so it never re-reads V.
// ---------------------------------------------------------------------------
__global__ __launch_bounds__(256, 2) void proj_v(
    const float* __restrict__ x, const unsigned short* __restrict__ Wt,
    const int* __restrict__ lens, unsigned short* __restrict__ Vz,
    float* __restrict__ mvg)
{
  __shared__ float Als[2][64 * 64];            // 32 KiB A dbuf
  const int tid = threadIdx.x;
  const int wave = tid >> 6, lane = tid & 63;
  const int quad = lane >> 4, mm = lane & 15;
  const int rb = blockIdx.x * 64;
  const int bidx = blockIdx.x >> 5;
  const int len = lens[bidx];
  if ((rb & (SL - 1)) >= len) return;          // dead block: outputs never read

  f32x4 acc[4][2];
  #pragma unroll
  for (int i = 0; i < 4; ++i) { acc[i][0] = f32x4{0.f,0.f,0.f,0.f}; acc[i][1] = f32x4{0.f,0.f,0.f,0.f}; }

  const float* asrc[4];
  #pragma unroll
  for (int i = 0; i < 4; ++i) {
    const int rl_ = wave * 16 + i * 4 + (lane >> 4);
    const int cc  = (lane & 8) | ((lane & 7) ^ (rl_ & 7));
    asrc[i] = x + (size_t)(rb + rl_) * EM + cc * 4;
  }
  int soff[2][2];
  #pragma unroll
  for (int ks = 0; ks < 2; ++ks) {
    soff[ks][0] = (ks * 8 + ((quad * 2)     ^ (mm & 7))) * 4;
    soff[ks][1] = (ks * 8 + ((quad * 2 + 1) ^ (mm & 7))) * 4;
  }
  const unsigned short* bbase[2][2];
  #pragma unroll
  for (int lo = 0; lo < 2; ++lo)
    #pragma unroll
    for (int ks = 0; ks < 2; ++ks) {
      const int nrow = (wave * 2 + lo) * 16 + mm;
      const int pp = (ks * 4 + quad) ^ (mm & 7);
      const int cs = nrow * 8 + pp;            // cs < 1024
      bbase[lo][ks] = Wt + ((size_t)2 * 16384 + cs) * 8;
    }

  #pragma unroll
  for (int i = 0; i < 4; ++i)
    dma16(asrc[i],      (char*)Als[0] + wave * 4096 + i * 1024);
  #pragma unroll
  for (int i = 0; i < 4; ++i)
    dma16(asrc[i] + 64, (char*)Als[1] + wave * 4096 + i * 1024);
  __asm__ volatile("s_waitcnt vmcnt(4)" ::: "memory");
  __builtin_amdgcn_s_barrier();

  #pragma unroll 1
  for (int kc = 0; kc < 16; ++kc) {
    SBAR();
    bf16x8 bfr[2][2];
    #pragma unroll
    for (int lo = 0; lo < 2; ++lo)
      #pragma unroll
      for (int ks = 0; ks < 2; ++ks)
        bfr[lo][ks] = *(const bf16x8*)(bbase[lo][ks] + (size_t)kc * 8192);
    bf16x8 af[4][2];
    #pragma unroll
    for (int rt = 0; rt < 4; ++rt) {
      const float* rbase = Als[kc & 1] + (rt * 16 + mm) * 64;
      #pragma unroll
      for (int ks = 0; ks < 2; ++ks) {
        f32x4 a0 = *(const f32x4*)(rbase + soff[ks][0]);
        f32x4 a1 = *(const f32x4*)(rbase + soff[ks][1]);
        af[rt][ks] = cvt8(a0, a1);
      }
    }
    __asm__ volatile("s_waitcnt lgkmcnt(0)" ::: "memory");
    SBAR();
    __builtin_amdgcn_s_barrier();
    {
      const int kn = (kc + 2 < 16) ? (kc + 2) : 15;
      #pragma unroll
      for (int i = 0; i < 4; ++i)
        dma16(asrc[i] + kn * 64, (char*)Als[kc & 1] + wave * 4096 + i * 1024);
    }
    #pragma unroll
    for (int lo = 0; lo < 2; ++lo)
      #pragma unroll
      for (int ks = 0; ks < 2; ++ks)
        #pragma unroll
        for (int rt = 0; rt < 4; ++rt)
          acc[rt][lo] = mfma16(af[rt][ks], bfr[lo][ks], acc[rt][lo]);
    __builtin_amdgcn_s_barrier();
  }
  __asm__ volatile("s_waitcnt vmcnt(0)" ::: "memory");

  #pragma unroll
  for (int rt = 0; rt < 4; ++rt)
    #pragma unroll
    for (int lo = 0; lo < 2; ++lo) {
      const int d = (wave * 2 + lo) * 16 + mm;
      const int row0 = rb + rt * 16 + quad * 4;
      const int b = row0 >> 11, j0 = row0 & (SL - 1);
      u16x4 pk = u16x4{ f2bf(acc[rt][lo][0]), f2bf(acc[rt][lo][1]),
                        f2bf(acc[rt][lo][2]), f2bf(acc[rt][lo][3]) };
      size_t off = (size_t)b * DKD * SL + (size_t)d * SL + (j0 & ~63)
                 + ((((j0 >> 3) & 7) ^ (d & 7)) * 8) + (j0 & 7);
      *(u16x4*)(Vz + off) = pk;
    }

  // ---- mean-V accumulation: sum valid rows (j < len), f32, one atomic/(d) ----
  const int jb = rb & (SL - 1);
  #pragma unroll
  for (int lo = 0; lo < 2; ++lo) {
    const int d = (wave * 2 + lo) * 16 + mm;
    float part = 0.f;
    #pragma unroll
    for (int rt = 0; rt < 4; ++rt) {
      const int jr = jb + rt * 16 + quad * 4;
      #pragma unroll
      for (int reg = 0; reg < 4; ++reg)
        if (jr + reg < len) part += acc[rt][lo][reg];
    }
    part += __shfl_xor(part, 16);            // quad ^ 1
    part += __shfl_xor(part, 32);            // quad ^ 2
    if (quad == 0) atomicAdd(mvg + bidx * DKD + d, part);
  }
}

// ---------------------------------------------------------------------------
// attn: flash attention, 64 q-rows/block, pipelined 64-key blocks (dbuf DMA).
// l accumulated as a 9th PV tile against a ones-B fragment (no sum-shuffles;
// alpha rescale applies to it automatically). Fully-padded query blocks
// broadcast mvg[b]/len — no V reads.
// ---------------------------------------------------------------------------
__global__ __launch_bounds__(256, 2) void attn(
    const unsigned short* __restrict__ Qw, const unsigned short* __restrict__ Kz,
    const unsigned short* __restrict__ Vz, const float* __restrict__ mvg,
    const int* __restrict__ lens, float* __restrict__ out)
{
  __shared__ unsigned short Ks[2][64 * 128];   // [j][16 chunks x 8], swz c^(j&15)
  __shared__ unsigned short Vs[2][128 * 64];   // [d][8 chunks x 8],  swz c^(d&7)
  __shared__ unsigned short Ps[4][16 * 72];    // per-wave P [q][j+pad8]
  const int tid = threadIdx.x;
  const int wave = tid >> 6, lane = tid & 63;
  const int quad = lane >> 4, mm = lane & 15;
  const int b = blockIdx.y;
  const int qb = ((int)gridDim.x - 1 - (int)blockIdx.x) * 64;  // heavy blocks first
  const int len = lens[b];

  if (qb >= len) {
    // ---- mean path: every row = mvg[b]/len (precomputed by proj_v) ----
    const int dd = (tid & 31) * 4;
    const int r0 = tid >> 5;                 // 0..7
    const f32x4 m4 = *(const f32x4*)(mvg + b * DKD + dd);
    const float inv = 1.0f / (float)len;
    const f32x4 val = f32x4{ m4[0]*inv, m4[1]*inv, m4[2]*inv, m4[3]*inv };
    #pragma unroll
    for (int it = 0; it < 8; ++it) {
      const int row = qb + it * 8 + r0;
      *(f32x4*)(out + ((size_t)b * SL + row) * DKD + dd) = val;
    }
    return;
  }

  const int kend = min(qb + 64, len);
  const int nblk = (kend + 63) >> 6;
  const int irow0 = qb + wave * 16 + quad * 4;

  bf16x8 aQ[4];
  {
    const unsigned short* qbase =
        Qw + (size_t)(b * SL + qb + wave * 16 + mm) * DKD + quad * 8;
    #pragma unroll
    for (int cc = 0; cc < 4; ++cc) aQ[cc] = *(const bf16x8*)(qbase + cc * 32);
  }
  bf16x8 onesb;
  #pragma unroll
  for (int i = 0; i < 8; ++i) onesb[i] = (__bf16)1.0f;

  float mr[4];
  #pragma unroll
  for (int r = 0; r < 4; ++r) mr[r] = -__builtin_inff();
  f32x4 acc[8];
  #pragma unroll
  for (int i = 0; i < 8; ++i) acc[i] = f32x4{0.f,0.f,0.f,0.f};
  f32x4 accl = f32x4{0.f,0.f,0.f,0.f};       // l = P @ ones, rescaled with acc

  // prologue DMA: block 0 -> buf 0
  #pragma unroll
  for (int it = 0; it < 4; ++it) {
    int s = it * 256 + tid;
    dma16(Kz + (size_t)(b * SL) * DKD + (size_t)s * 8,
          (char*)Ks[0] + (it * 256 + wave * 64) * 16);
  }
  #pragma unroll
  for (int it = 0; it < 4; ++it) {
    int s = it * 256 + tid;
    int d = s >> 3, p = s & 7;
    dma16(Vz + (size_t)b * DKD * SL + (size_t)d * SL + p * 8,
          (char*)Vs[0] + (it * 256 + wave * 64) * 16);
  }

  #pragma unroll 1
  for (int blk = 0; blk < nblk; ++blk) {
    const int kb = blk * 64;
    __syncthreads();                       // drains DMA(blk)
    if (blk + 1 < nblk) {                  // issue next block's DMA
      const int kb1 = kb + 64;
      const int nb = (blk + 1) & 1;
      #pragma unroll
      for (int it = 0; it < 4; ++it) {
        int s = it * 256 + tid;
        dma16(Kz + (size_t)(b * SL + kb1) * DKD + (size_t)s * 8,
              (char*)Ks[nb] + (it * 256 + wave * 64) * 16);
      }
      #pragma unroll
      for (int it = 0; it < 4; ++it) {
        int s = it * 256 + tid;
        int d = s >> 3, p = s & 7;
        dma16(Vz + (size_t)b * DKD * SL + (size_t)d * SL + kb1 + p * 8,
              (char*)Vs[nb] + (it * 256 + wave * 64) * 16);
      }
    }
    const unsigned short* kbuf = Ks[blk & 1];
    const unsigned short* vbuf = Vs[blk & 1];

    // S = Q K^T : 4 key-tiles
    f32x4 s4[4];
    #pragma unroll
    for (int nt = 0; nt < 4; ++nt) {
      f32x4 c = f32x4{0.f,0.f,0.f,0.f};
      const int j = nt * 16 + mm;
      #pragma unroll
      for (int cc = 0; cc < 4; ++cc) {
        const int pp = (cc * 4 + quad) ^ mm;
        bf16x8 kf = *(const bf16x8*)(kbuf + j * 128 + pp * 8);
        c = mfma16(aQ[cc], kf, c);
      }
      s4[nt] = c;
    }

    float alpha[4];
    #pragma unroll
    for (int reg = 0; reg < 4; ++reg) {
      const int jl = min(irow0 + reg + 1, len);
      float v0 = (kb + mm      < jl) ? s4[0][reg] : -__builtin_inff();
      float v1 = (kb + 16 + mm < jl) ? s4[1][reg] : -__builtin_inff();
      float v2 = (kb + 32 + mm < jl) ? s4[2][reg] : -__builtin_inff();
      float v3 = (kb + 48 + mm < jl) ? s4[3][reg] : -__builtin_inff();
      float mx = fmaxf(fmaxf(v0, v1), fmaxf(v2, v3));
      #pragma unroll
      for (int xm = 1; xm < 16; xm <<= 1) mx = fmaxf(mx, __shfl_xor(mx, xm));
      const float mn = fmaxf(mr[reg], mx);
      alpha[reg] = __builtin_amdgcn_exp2f(mr[reg] - mn);
      const float p0 = __builtin_amdgcn_exp2f(v0 - mn);
      const float p1 = __builtin_amdgcn_exp2f(v1 - mn);
      const float p2 = __builtin_amdgcn_exp2f(v2 - mn);
      const float p3 = __builtin_amdgcn_exp2f(v3 - mn);
      mr[reg] = mn;
      const int prow = quad * 4 + reg;
      Ps[wave][prow * 72 + mm]      = f2bf(p0);
      Ps[wave][prow * 72 + 16 + mm] = f2bf(p1);
      Ps[wave][prow * 72 + 32 + mm] = f2bf(p2);
      Ps[wave][prow * 72 + 48 + mm] = f2bf(p3);
    }
    #pragma unroll
    for (int nt = 0; nt < 8; ++nt) {
      f32x4 a = acc[nt];
      a[0] *= alpha[0]; a[1] *= alpha[1]; a[2] *= alpha[2]; a[3] *= alpha[3];
      acc[nt] = a;
    }
    accl[0] *= alpha[0]; accl[1] *= alpha[1];
    accl[2] *= alpha[2]; accl[3] *= alpha[3];
    __asm__ volatile("s_waitcnt lgkmcnt(0)" ::: "memory");  // P writes -> reads
    bf16x8 aP[2];
    #pragma unroll
    for (int ks = 0; ks < 2; ++ks)
      aP[ks] = *(const bf16x8*)(&Ps[wave][mm * 72 + ks * 32 + quad * 8]);
    #pragma unroll
    for (int ks = 0; ks < 2; ++ks) {
      #pragma unroll
      for (int nt = 0; nt < 8; ++nt) {
        const int pp = (ks * 4 + quad) ^ (mm & 7);
        bf16x8 vf = *(const bf16x8*)(vbuf + (nt * 16 + mm) * 64 + pp * 8);
        acc[nt] = mfma16(aP[ks], vf, acc[nt]);
      }
      accl = mfma16(aP[ks], onesb, accl);    // row-sum tile (all cols equal)
    }
  }

  #pragma unroll
  for (int reg = 0; reg < 4; ++reg) {
    const float rl = 1.0f / accl[reg];
    const size_t base = ((size_t)b * SL + irow0 + reg) * DKD + mm;
    #pragma unroll
    for (int nt = 0; nt < 8; ++nt)
      out[base + nt * 16] = acc[nt][reg] * rl;
  }
}

// ---------------------------------------------------------------------------
extern "C" void kernel_launch(void* const* d_in, const int* in_sizes, int n_in,
                              void* d_out, int out_size, void* d_ws, size_t ws_size,
                              hipStream_t stream) {
  const float* x    = (const float*)d_in[0];
  const float* ctx  = (const float*)d_in[1];
  const int*   lens = (const int*)d_in[2];
  const float* Wq   = (const float*)d_in[3];
  const float* Wk   = (const float*)d_in[4];
  const float* Wv   = (const float*)d_in[5];
  float* out = (float*)d_out;

  const size_t QKV = (size_t)NB * SL * DKD * sizeof(unsigned short); // 8 MiB each
  const size_t WTSZ = (size_t)3 * 16 * 128 * 8 * 8 * sizeof(unsigned short); // 768 KiB
  const size_t MVSZ = (size_t)NB * DKD * sizeof(float);              // 8 KiB
  if (ws_size < 3 * QKV + WTSZ + MVSZ) return;
  unsigned short* Qws = (unsigned short*)d_ws;
  unsigned short* Kzs = (unsigned short*)((char*)d_ws + QKV);
  unsigned short* Vzs = (unsigned short*)((char*)d_ws + 2 * QKV);
  unsigned short* Wt  = (unsigned short*)((char*)d_ws + 3 * QKV);
  float*          mvg = (float*)((char*)d_ws + 3 * QKV + WTSZ);

  prep_w <<<dim3(48), 256, 0, stream>>>(Wq, Wk, Wv, Wt, mvg);
  proj_qk<<<dim3(NB * SL / 64), 256, 0, stream>>>(ctx, Wt, lens, Qws, Kzs);
  proj_v <<<dim3(NB * SL / 64), 256, 0, stream>>>(x, Wt, lens, Vzs, mvg);
  attn   <<<dim3(SL / 64, NB), 256, 0, stream>>>(Qws, Kzs, Vzs, mvg, lens, out);
}